// Round 6
// baseline (664.153 us; speedup 1.0000x reference)
//
#include <hip/hip_runtime.h>
#include <hip/hip_bf16.h>

typedef __bf16 bf16x8 __attribute__((ext_vector_type(8)));
typedef float  f32x4  __attribute__((ext_vector_type(4)));

__device__ __forceinline__ unsigned short f2bf(float f) {
    union { float f; unsigned int u; } v; v.f = f;
    unsigned int r = v.u + 0x7fffu + ((v.u >> 16) & 1u);
    return (unsigned short)(r >> 16);
}
__device__ __forceinline__ float bf2f(unsigned short h) {
    union { unsigned int u; float f; } v; v.u = ((unsigned int)h) << 16;
    return v.f;
}

typedef __attribute__((address_space(3))) unsigned int lds_u32_t;
typedef const __attribute__((address_space(1))) unsigned int glb_u32_t;
__device__ __forceinline__ void gl_lds16(const void* g, void* l) {
    __builtin_amdgcn_global_load_lds((glb_u32_t*)g, (lds_u32_t*)l, 16, 0, 0);
}

// ---------------- cast fp32 -> bf16 (flat) ----------------
__global__ void k_cast(const float* __restrict__ in, unsigned short* __restrict__ out, int n) {
    int i = (blockIdx.x * blockDim.x + threadIdx.x) * 4;
    if (i + 3 < n) {
        float4 v = *reinterpret_cast<const float4*>(in + i);
        ushort4 o;
        o.x = f2bf(v.x); o.y = f2bf(v.y); o.z = f2bf(v.z); o.w = f2bf(v.w);
        *reinterpret_cast<ushort4*>(out + i) = o;
    }
}

// ---------------- transpose + cast: in [K][N] f32 -> out [N][K] bf16 ----------------
__global__ void k_transpose_cast(const float* __restrict__ in, unsigned short* __restrict__ out,
                                 int K, int N) {
    __shared__ float tile[32][33];
    int n0 = blockIdx.x * 32, k0 = blockIdx.y * 32;
    int tx = threadIdx.x, ty = threadIdx.y; // block (32,8)
    #pragma unroll
    for (int i = 0; i < 4; ++i)
        tile[ty + i * 8][tx] = in[(size_t)(k0 + ty + i * 8) * N + n0 + tx];
    __syncthreads();
    #pragma unroll
    for (int i = 0; i < 4; ++i)
        out[(size_t)(n0 + ty + i * 8) * K + k0 + tx] = f2bf(tile[tx][ty + i * 8]);
}

// ---------------- bf16 MFMA GEMM (m97 structure): out = A[M,K] * Bt[N,K]^T + bias ----------------
// mode 0: out bf16 row-major [M,N];  mode 2: out fp32 row-major [M,N]
__global__ __launch_bounds__(256) void k_gemm(
    const unsigned short* __restrict__ A, int lda,
    const unsigned short* __restrict__ Bt, int ldb,
    const float* __restrict__ bias,
    void* __restrict__ out,
    int M, int N, int K, int mode, float scale)
{
    __shared__ unsigned short As[128 * 32];
    __shared__ unsigned short Bs[128 * 32];
    int tid  = threadIdx.x;
    int lane = tid & 63, wv = tid >> 6;
    int quad = lane >> 4, l16 = lane & 15;
    int bm = blockIdx.y * 128, bn = blockIdx.x * 128;
    int wm = (wv >> 1) * 64,  wn = (wv & 1) * 64;

    f32x4 acc[4][4] = {};
    int srow = tid >> 2, scol = (tid & 3) * 8;

    for (int k0 = 0; k0 < K; k0 += 32) {
        #pragma unroll
        for (int s = 0; s < 2; ++s) {
            int row = s * 64 + srow;
            gl_lds16(&A[(size_t)(bm + row) * lda + k0 + scol], &As[(s * 256 + wv * 64) * 8]);
            gl_lds16(&Bt[(size_t)(bn + row) * ldb + k0 + scol], &Bs[(s * 256 + wv * 64) * 8]);
        }
        __syncthreads();
        bf16x8 af[4], bfv[4];
        #pragma unroll
        for (int mi = 0; mi < 4; ++mi)
            af[mi] = *reinterpret_cast<const bf16x8*>(&As[(wm + mi * 16 + l16) * 32 + quad * 8]);
        #pragma unroll
        for (int ni = 0; ni < 4; ++ni)
            bfv[ni] = *reinterpret_cast<const bf16x8*>(&Bs[(wn + ni * 16 + l16) * 32 + quad * 8]);
        #pragma unroll
        for (int mi = 0; mi < 4; ++mi)
            #pragma unroll
            for (int ni = 0; ni < 4; ++ni)
                acc[mi][ni] = __builtin_amdgcn_mfma_f32_16x16x32_bf16(af[mi], bfv[ni], acc[mi][ni], 0, 0, 0);
        __syncthreads();
    }

    #pragma unroll
    for (int mi = 0; mi < 4; ++mi) {
        #pragma unroll
        for (int ni = 0; ni < 4; ++ni) {
            int col = bn + wn + ni * 16 + l16;
            float bsv = bias[col];
            #pragma unroll
            for (int ri = 0; ri < 4; ++ri) {
                int row = bm + wm + mi * 16 + quad * 4 + ri;
                float val = (acc[mi][ni][ri] + bsv) * scale;
                if (mode == 0)
                    reinterpret_cast<unsigned short*>(out)[(size_t)row * N + col] = f2bf(val);
                else
                    reinterpret_cast<float*>(out)[(size_t)row * N + col] = val;
            }
        }
    }
}

// ---------------- fused q/k/v projections -> per-branch gathered layouts ----------------
// Qg/Kg: [slot14][bh32][idx512][d64]; Vtg: [slot14][bh32][d64][idx512]
// slot: 0..7 br0 (w=512,r=1), 8..11 br1 (w=1024,r=2), 12..13 br2 (w=2048,r=4).
// Position t of head h is in branch br iff (t^h) & (r-1) == 0; idx = (t % w) >> br.
// q (z==0) pre-scaled by D^-0.5 * log2(e) so attention uses exp2 directly.
__global__ __launch_bounds__(256) void k_gemm3(
    const unsigned short* __restrict__ A0, int lda,
    const unsigned short* __restrict__ wT3,
    const float* __restrict__ b_q, const float* __restrict__ b_k, const float* __restrict__ b_v,
    unsigned short* __restrict__ Qg, unsigned short* __restrict__ Kg,
    unsigned short* __restrict__ Vtg)
{
    __shared__ unsigned short As[128 * 32];
    __shared__ unsigned short Bs[128 * 32];
    int z = blockIdx.z;
    const unsigned short* A  = A0 + z * 1024;
    const unsigned short* Bt = wT3 + (size_t)z * 1024 * 1024;
    const float* bias = (z == 0) ? b_q : (z == 1) ? b_k : b_v;
    float scale = (z == 0) ? 0.1803368801f : 1.f;   // 0.125 * log2(e)
    unsigned short* dstQK = (z == 0) ? Qg : Kg;
    bool isV = (z == 2);

    int tid  = threadIdx.x;
    int lane = tid & 63, wv = tid >> 6;
    int quad = lane >> 4, l16 = lane & 15;
    int bm = blockIdx.y * 128, bn = blockIdx.x * 128;
    int wm = (wv >> 1) * 64,  wn = (wv & 1) * 64;

    f32x4 acc[4][4] = {};
    int srow = tid >> 2, scol = (tid & 3) * 8;

    for (int k0 = 0; k0 < 1024; k0 += 32) {
        #pragma unroll
        for (int s = 0; s < 2; ++s) {
            int row = s * 64 + srow;
            gl_lds16(&A[(size_t)(bm + row) * lda + k0 + scol], &As[(s * 256 + wv * 64) * 8]);
            gl_lds16(&Bt[(size_t)(bn + row) * 1024 + k0 + scol], &Bs[(s * 256 + wv * 64) * 8]);
        }
        __syncthreads();
        bf16x8 af[4], bfv[4];
        #pragma unroll
        for (int mi = 0; mi < 4; ++mi)
            af[mi] = *reinterpret_cast<const bf16x8*>(&As[(wm + mi * 16 + l16) * 32 + quad * 8]);
        #pragma unroll
        for (int ni = 0; ni < 4; ++ni)
            bfv[ni] = *reinterpret_cast<const bf16x8*>(&Bs[(wn + ni * 16 + l16) * 32 + quad * 8]);
        #pragma unroll
        for (int mi = 0; mi < 4; ++mi)
            #pragma unroll
            for (int ni = 0; ni < 4; ++ni)
                acc[mi][ni] = __builtin_amdgcn_mfma_f32_16x16x32_bf16(af[mi], bfv[ni], acc[mi][ni], 0, 0, 0);
        __syncthreads();
    }

    #pragma unroll
    for (int mi = 0; mi < 4; ++mi) {
        #pragma unroll
        for (int ni = 0; ni < 4; ++ni) {
            int col = bn + wn + ni * 16 + l16;
            float bsv = bias[col];
            int hh = col >> 6, d = col & 63;
            #pragma unroll
            for (int ri = 0; ri < 4; ++ri) {
                int row = bm + wm + mi * 16 + quad * 4 + ri;
                float val = (acc[mi][ni][ri] + bsv) * scale;
                unsigned short bv = f2bf(val);
                int b = row >> 12, t = row & 4095;
                int bh = b * 16 + hh;
                {   // branch 0 (always covered)
                    int slot = t >> 9, idx = t & 511;
                    size_t sbh = (size_t)(slot * 32 + bh);
                    if (isV) Vtg[(sbh * 64 + d) * 512 + idx] = bv;
                    else     dstQK[(sbh * 512 + idx) * 64 + d] = bv;
                }
                if (((t ^ hh) & 1) == 0) {   // branch 1
                    int slot = 8 + (t >> 10), idx = (t & 1023) >> 1;
                    size_t sbh = (size_t)(slot * 32 + bh);
                    if (isV) Vtg[(sbh * 64 + d) * 512 + idx] = bv;
                    else     dstQK[(sbh * 512 + idx) * 64 + d] = bv;
                }
                if (((t ^ hh) & 3) == 0) {   // branch 2
                    int slot = 12 + (t >> 11), idx = (t & 2047) >> 2;
                    size_t sbh = (size_t)(slot * 32 + bh);
                    if (isV) Vtg[(sbh * 64 + d) * 512 + idx] = bv;
                    else     dstQK[(sbh * 512 + idx) * 64 + d] = bv;
                }
            }
        }
    }
}

// ---------------- dilated attention: barrier-free, direct global fragment loads ----------------
__global__ __launch_bounds__(256, 3) void k_attn(
    const unsigned short* __restrict__ Qg,
    const unsigned short* __restrict__ Kg,
    const unsigned short* __restrict__ Vtg,
    unsigned short* __restrict__ Og,
    float* __restrict__ Lg)
{
    __shared__ unsigned short Ps[4][16 * 72];   // per-wave P buffer (16 rows x 64 + pad)

    int tid  = threadIdx.x;
    int lane = tid & 63, wv = tid >> 6;
    int quad = lane >> 4, l16 = lane & 15;
    int qt = blockIdx.x, ys = blockIdx.y, bh = blockIdx.z;
    size_t sb = (size_t)(ys * 32 + bh) * (512 * 64);
    const unsigned short* qp = Qg + sb;
    const unsigned short* kp = Kg + sb;
    const unsigned short* vp = Vtg + sb;
    unsigned short* op = Og + sb;
    float* lp = Lg + (size_t)(ys * 32 + bh) * 512;
    unsigned short* pw = Ps[wv];

    int rw = qt * 128 + wv * 32;   // first q row of this wave (segment-local)

    bf16x8 qf[2][2];
    #pragma unroll
    for (int m16 = 0; m16 < 2; ++m16)
        #pragma unroll
        for (int kk = 0; kk < 2; ++kk)
            qf[m16][kk] = *reinterpret_cast<const bf16x8*>(
                &qp[(size_t)(rw + m16 * 16 + l16) * 64 + kk * 32 + quad * 8]);

    f32x4 acc[2][4] = {};
    float l4[2][4] = {};
    int jt_end = 2 * qt + (wv >> 1);

    for (int jt = 0; jt <= jt_end; ++jt) {
        bf16x8 kf[4][2];
        #pragma unroll
        for (int nt = 0; nt < 4; ++nt)
            #pragma unroll
            for (int kk = 0; kk < 2; ++kk)
                kf[nt][kk] = *reinterpret_cast<const bf16x8*>(
                    &kp[(size_t)(jt * 64 + nt * 16 + l16) * 64 + kk * 32 + quad * 8]);

        f32x4 sacc[2][4];
        #pragma unroll
        for (int m16 = 0; m16 < 2; ++m16)
            #pragma unroll
            for (int nt = 0; nt < 4; ++nt) {
                f32x4 s4 = {};
                s4 = __builtin_amdgcn_mfma_f32_16x16x32_bf16(qf[m16][0], kf[nt][0], s4, 0, 0, 0);
                s4 = __builtin_amdgcn_mfma_f32_16x16x32_bf16(qf[m16][1], kf[nt][1], s4, 0, 0, 0);
                sacc[m16][nt] = s4;
            }

        bf16x8 vf[4][2];
        #pragma unroll
        for (int dt = 0; dt < 4; ++dt)
            #pragma unroll
            for (int kk = 0; kk < 2; ++kk)
                vf[dt][kk] = *reinterpret_cast<const bf16x8*>(
                    &vp[(size_t)(dt * 16 + l16) * 512 + jt * 64 + kk * 32 + quad * 8]);

        #pragma unroll
        for (int m16 = 0; m16 < 2; ++m16) {
            int rowbase = rw + m16 * 16;
            if (jt * 64 + 63 > rowbase) {
                #pragma unroll
                for (int nt = 0; nt < 4; ++nt)
                    #pragma unroll
                    for (int ri = 0; ri < 4; ++ri) {
                        int kj = jt * 64 + nt * 16 + l16, qi = rowbase + quad * 4 + ri;
                        if (kj > qi) sacc[m16][nt][ri] = -1e30f;
                    }
            }
            #pragma unroll
            for (int nt = 0; nt < 4; ++nt)
                #pragma unroll
                for (int ri = 0; ri < 4; ++ri) {
                    float p = exp2f(sacc[m16][nt][ri]);
                    sacc[m16][nt][ri] = p;
                    l4[m16][ri] += p;
                }
            #pragma unroll
            for (int j = 0; j < 4; ++j) {
                int nt = (j + quad) & 3;
                #pragma unroll
                for (int ri = 0; ri < 4; ++ri)
                    pw[(quad * 4 + ri) * 72 + nt * 16 + l16] = f2bf(sacc[m16][nt][ri]);
            }
            bf16x8 pf[2];
            #pragma unroll
            for (int kk = 0; kk < 2; ++kk)
                pf[kk] = *reinterpret_cast<const bf16x8*>(&pw[l16 * 72 + kk * 32 + quad * 8]);
            #pragma unroll
            for (int dt = 0; dt < 4; ++dt) {
                f32x4 a4 = acc[m16][dt];
                a4 = __builtin_amdgcn_mfma_f32_16x16x32_bf16(pf[0], vf[dt][0], a4, 0, 0, 0);
                a4 = __builtin_amdgcn_mfma_f32_16x16x32_bf16(pf[1], vf[dt][1], a4, 0, 0, 0);
                acc[m16][dt] = a4;
            }
        }
    }

    #pragma unroll
    for (int m16 = 0; m16 < 2; ++m16)
        #pragma unroll
        for (int ri = 0; ri < 4; ++ri) {
            float l = l4[m16][ri];
            l += __shfl_xor(l, 1);
            l += __shfl_xor(l, 2);
            l += __shfl_xor(l, 4);
            l += __shfl_xor(l, 8);
            l4[m16][ri] = l;
        }

    #pragma unroll
    for (int m16 = 0; m16 < 2; ++m16) {
        #pragma unroll
        for (int dt = 0; dt < 4; ++dt)
            #pragma unroll
            for (int ri = 0; ri < 4; ++ri) {
                int row = rw + m16 * 16 + quad * 4 + ri;
                op[(size_t)row * 64 + dt * 16 + l16] = f2bf(acc[m16][dt][ri] / l4[m16][ri]);
            }
        if (l16 == 0) {
            #pragma unroll
            for (int ri = 0; ri < 4; ++ri) {
                int row = rw + m16 * 16 + quad * 4 + ri;
                lp[row] = __logf(l4[m16][ri]);
            }
        }
    }
}

// ---------------- combine branches via LSE weights (coverage computed analytically) ----------------
__global__ void k_combine(const unsigned short* __restrict__ Og,
                          const float* __restrict__ Lg,
                          unsigned short* __restrict__ yb)
{
    int g   = blockIdx.x * blockDim.x + threadIdx.x; // 131072 rows * 8 parts
    int row = g >> 3;
    int d0  = (g & 7) * 8;
    int bh = row >> 12, t = row & 4095;
    int b = bh >> 4, h = bh & 15;

    int slot0 = t >> 9,         idx0 = t & 511;
    int slot1 = 8 + (t >> 10),  idx1 = (t & 1023) >> 1;
    int slot2 = 12 + (t >> 11), idx2 = (t & 2047) >> 2;
    size_t r0 = (size_t)(slot0 * 32 + bh) * 512 + idx0;
    size_t r1 = (size_t)(slot1 * 32 + bh) * 512 + idx1;
    size_t r2 = (size_t)(slot2 * 32 + bh) * 512 + idx2;
    bool c1 = ((t ^ h) & 1) == 0;
    bool c2 = ((t ^ h) & 3) == 0;

    float L0 = Lg[r0];
    float L1 = c1 ? Lg[r1] : -1e30f;
    float L2 = c2 ? Lg[r2] : -1e30f;
    float m  = fmaxf(L0, fmaxf(L1, L2));
    float w0 = __expf(L0 - m), w1 = __expf(L1 - m), w2 = __expf(L2 - m);
    float inv = 1.f / (w0 + w1 + w2);

    uint4 v0 = *reinterpret_cast<const uint4*>(&Og[r0 * 64 + d0]);
    uint4 v1 = *reinterpret_cast<const uint4*>(&Og[r1 * 64 + d0]);
    uint4 v2 = *reinterpret_cast<const uint4*>(&Og[r2 * 64 + d0]);
    const unsigned short* p0 = reinterpret_cast<const unsigned short*>(&v0);
    const unsigned short* p1 = reinterpret_cast<const unsigned short*>(&v1);
    const unsigned short* p2 = reinterpret_cast<const unsigned short*>(&v2);
    unsigned short o[8];
    #pragma unroll
    for (int u = 0; u < 8; ++u)
        o[u] = f2bf((w0 * bf2f(p0[u]) + w1 * bf2f(p1[u]) + w2 * bf2f(p2[u])) * inv);
    size_t yidx = (((size_t)b * 4096 + t) * 1024) + (size_t)h * 64 + d0;
    *reinterpret_cast<uint4*>(&yb[yidx]) = *reinterpret_cast<const uint4*>(o);
}

extern "C" void kernel_launch(void* const* d_in, const int* in_sizes, int n_in,
                              void* d_out, int out_size, void* d_ws, size_t ws_size,
                              hipStream_t stream)
{
    const float* x        = (const float*)d_in[0];
    const float* c_attn_w = (const float*)d_in[1];
    const float* c_attn_b = (const float*)d_in[2];
    const float* q_w      = (const float*)d_in[3];
    const float* q_b      = (const float*)d_in[4];
    const float* k_w      = (const float*)d_in[5];
    const float* k_b      = (const float*)d_in[6];
    const float* v_w      = (const float*)d_in[7];
    const float* v_b      = (const float*)d_in[8];
    const float* o_w      = (const float*)d_in[9];
    const float* o_b      = (const float*)d_in[10];

    char* ws = (char*)d_ws;
    size_t off = 0;
    auto alloc = [&](size_t bytes) -> char* {
        char* p = ws + off; off += (bytes + 255) & ~(size_t)255; return p;
    };
    const size_t GSZ = 14ull * 32 * 512 * 64;   // gathered tensor elements
    unsigned short* xb    = (unsigned short*)alloc(8192ull * 1024 * 2);
    unsigned short* wqkvT = (unsigned short*)alloc(3072ull * 1024 * 2);
    unsigned short* wqT   = (unsigned short*)alloc(1024ull * 1024 * 2);   // wq/wk/wv contiguous
    unsigned short* wkT   = (unsigned short*)alloc(1024ull * 1024 * 2);
    unsigned short* wvT   = (unsigned short*)alloc(1024ull * 1024 * 2);
    unsigned short* woT   = (unsigned short*)alloc(1024ull * 1024 * 2);
    unsigned short* qkvb  = (unsigned short*)alloc(8192ull * 3072 * 2);
    unsigned short* Qg    = (unsigned short*)alloc(GSZ * 2);
    unsigned short* Kg    = (unsigned short*)alloc(GSZ * 2);
    unsigned short* Vtg   = (unsigned short*)alloc(GSZ * 2);
    float*          Lg    = (float*)alloc(14ull * 32 * 512 * 4);
    unsigned short* Og    = qkvb;  // alias: qkvb dead after k_gemm3
    unsigned short* yb    = xb;    // alias: xb dead after qkv GEMM
    (void)wkT; (void)wvT;

    // 1. cast x to bf16
    k_cast<<<(8192 * 1024) / 1024, 256, 0, stream>>>(x, xb, 8192 * 1024);
    // 2. transpose-cast weights to [N][K] bf16
    k_transpose_cast<<<dim3(3072 / 32, 1024 / 32), dim3(32, 8), 0, stream>>>(c_attn_w, wqkvT, 1024, 3072);
    k_transpose_cast<<<dim3(32, 32), dim3(32, 8), 0, stream>>>(q_w, wqT, 1024, 1024);
    k_transpose_cast<<<dim3(32, 32), dim3(32, 8), 0, stream>>>(k_w, wkT, 1024, 1024);
    k_transpose_cast<<<dim3(32, 32), dim3(32, 8), 0, stream>>>(v_w, wvT, 1024, 1024);
    k_transpose_cast<<<dim3(32, 32), dim3(32, 8), 0, stream>>>(o_w, woT, 1024, 1024);
    // 3. qkv = x @ c_attn_w + b
    k_gemm<<<dim3(24, 64), 256, 0, stream>>>(xb, 1024, wqkvT, 1024, c_attn_b, qkvb, 8192, 3072, 1024, 0, 1.f);
    // 4. fused q/k/v projections -> gathered per-branch layouts (q pre-scaled by D^-0.5*log2e)
    k_gemm3<<<dim3(8, 64, 3), 256, 0, stream>>>(qkvb, 3072, wqT, q_b, k_b, v_b, Qg, Kg, Vtg);
    // 5. attention: all branches, barrier-free
    k_attn<<<dim3(4, 14, 32), 256, 0, stream>>>(Qg, Kg, Vtg, Og, Lg);
    // 6. combine branches -> y [B,T,C] bf16
    k_combine<<<4096, 256, 0, stream>>>(Og, Lg, yb);
    // 7. out = y @ o_w + o_b (fp32)
    k_gemm<<<dim3(8, 64), 256, 0, stream>>>(yb, 1024, woT, 1024, o_b, d_out, 8192, 1024, 1024, 2, 1.f);
}

// Round 7
// 506.988 us; speedup vs baseline: 1.3100x; 1.3100x over previous
//
#include <hip/hip_runtime.h>
#include <hip/hip_bf16.h>

typedef __bf16 bf16x8 __attribute__((ext_vector_type(8)));
typedef float  f32x4  __attribute__((ext_vector_type(4)));

__device__ __forceinline__ unsigned short f2bf(float f) {
    union { float f; unsigned int u; } v; v.f = f;
    unsigned int r = v.u + 0x7fffu + ((v.u >> 16) & 1u);
    return (unsigned short)(r >> 16);
}
__device__ __forceinline__ float bf2f(unsigned short h) {
    union { unsigned int u; float f; } v; v.u = ((unsigned int)h) << 16;
    return v.f;
}

typedef __attribute__((address_space(3))) unsigned int lds_u32_t;
typedef const __attribute__((address_space(1))) unsigned int glb_u32_t;
__device__ __forceinline__ void gl_lds16(const void* g, void* l) {
    __builtin_amdgcn_global_load_lds((glb_u32_t*)g, (lds_u32_t*)l, 16, 0, 0);
}

// ---------------- cast fp32 -> bf16 (flat) ----------------
__global__ void k_cast(const float* __restrict__ in, unsigned short* __restrict__ out, int n) {
    int i = (blockIdx.x * blockDim.x + threadIdx.x) * 4;
    if (i + 3 < n) {
        float4 v = *reinterpret_cast<const float4*>(in + i);
        ushort4 o;
        o.x = f2bf(v.x); o.y = f2bf(v.y); o.z = f2bf(v.z); o.w = f2bf(v.w);
        *reinterpret_cast<ushort4*>(out + i) = o;
    }
}

// ---------------- transpose + cast: in [K][N] f32 -> out [N][K] bf16 ----------------
__global__ void k_transpose_cast(const float* __restrict__ in, unsigned short* __restrict__ out,
                                 int K, int N) {
    __shared__ float tile[32][33];
    int n0 = blockIdx.x * 32, k0 = blockIdx.y * 32;
    int tx = threadIdx.x, ty = threadIdx.y; // block (32,8)
    #pragma unroll
    for (int i = 0; i < 4; ++i)
        tile[ty + i * 8][tx] = in[(size_t)(k0 + ty + i * 8) * N + n0 + tx];
    __syncthreads();
    #pragma unroll
    for (int i = 0; i < 4; ++i)
        out[(size_t)(n0 + ty + i * 8) * K + k0 + tx] = f2bf(tile[tx][ty + i * 8]);
}

// ---------------- bf16 MFMA GEMM (m97 structure): out = A[M,K] * Bt[N,K]^T + bias ----------------
// mode 0: out bf16 row-major [M,N];  mode 2: out fp32 row-major [M,N]
__global__ __launch_bounds__(256) void k_gemm(
    const unsigned short* __restrict__ A, int lda,
    const unsigned short* __restrict__ Bt, int ldb,
    const float* __restrict__ bias,
    void* __restrict__ out,
    int M, int N, int K, int mode, float scale)
{
    __shared__ unsigned short As[128 * 32];
    __shared__ unsigned short Bs[128 * 32];
    int tid  = threadIdx.x;
    int lane = tid & 63, wv = tid >> 6;
    int quad = lane >> 4, l16 = lane & 15;
    int bm = blockIdx.y * 128, bn = blockIdx.x * 128;
    int wm = (wv >> 1) * 64,  wn = (wv & 1) * 64;

    f32x4 acc[4][4] = {};
    int srow = tid >> 2, scol = (tid & 3) * 8;

    for (int k0 = 0; k0 < K; k0 += 32) {
        #pragma unroll
        for (int s = 0; s < 2; ++s) {
            int row = s * 64 + srow;
            gl_lds16(&A[(size_t)(bm + row) * lda + k0 + scol], &As[(s * 256 + wv * 64) * 8]);
            gl_lds16(&Bt[(size_t)(bn + row) * ldb + k0 + scol], &Bs[(s * 256 + wv * 64) * 8]);
        }
        __syncthreads();
        bf16x8 af[4], bfv[4];
        #pragma unroll
        for (int mi = 0; mi < 4; ++mi)
            af[mi] = *reinterpret_cast<const bf16x8*>(&As[(wm + mi * 16 + l16) * 32 + quad * 8]);
        #pragma unroll
        for (int ni = 0; ni < 4; ++ni)
            bfv[ni] = *reinterpret_cast<const bf16x8*>(&Bs[(wn + ni * 16 + l16) * 32 + quad * 8]);
        #pragma unroll
        for (int mi = 0; mi < 4; ++mi)
            #pragma unroll
            for (int ni = 0; ni < 4; ++ni)
                acc[mi][ni] = __builtin_amdgcn_mfma_f32_16x16x32_bf16(af[mi], bfv[ni], acc[mi][ni], 0, 0, 0);
        __syncthreads();
    }

    #pragma unroll
    for (int mi = 0; mi < 4; ++mi) {
        #pragma unroll
        for (int ni = 0; ni < 4; ++ni) {
            int col = bn + wn + ni * 16 + l16;
            float bsv = bias[col];
            #pragma unroll
            for (int ri = 0; ri < 4; ++ri) {
                int row = bm + wm + mi * 16 + quad * 4 + ri;
                float val = (acc[mi][ni][ri] + bsv) * scale;
                if (mode == 0)
                    reinterpret_cast<unsigned short*>(out)[(size_t)row * N + col] = f2bf(val);
                else
                    reinterpret_cast<float*>(out)[(size_t)row * N + col] = val;
            }
        }
    }
}

// ---------------- fused q/k/v projections -> per-branch gathered layouts ----------------
// Qg/Kg: [slot14][bh32][idx512][d64]; Vtg: [slot14][bh32][d64][idx512]
// slot: 0..7 br0 (w=512,r=1), 8..11 br1 (w=1024,r=2), 12..13 br2 (w=2048,r=4).
// Position t of head h is in branch br iff (t^h) & (r-1) == 0; idx = (t % w) >> br.
// q (z==0) pre-scaled by D^-0.5 * log2(e) so attention uses exp2 directly.
__global__ __launch_bounds__(256) void k_gemm3(
    const unsigned short* __restrict__ A0, int lda,
    const unsigned short* __restrict__ wT3,
    const float* __restrict__ b_q, const float* __restrict__ b_k, const float* __restrict__ b_v,
    unsigned short* __restrict__ Qg, unsigned short* __restrict__ Kg,
    unsigned short* __restrict__ Vtg)
{
    __shared__ unsigned short As[128 * 32];
    __shared__ unsigned short Bs[128 * 32];
    int z = blockIdx.z;
    const unsigned short* A  = A0 + z * 1024;
    const unsigned short* Bt = wT3 + (size_t)z * 1024 * 1024;
    const float* bias = (z == 0) ? b_q : (z == 1) ? b_k : b_v;
    float scale = (z == 0) ? 0.1803368801f : 1.f;   // 0.125 * log2(e)
    unsigned short* dstQK = (z == 0) ? Qg : Kg;
    bool isV = (z == 2);

    int tid  = threadIdx.x;
    int lane = tid & 63, wv = tid >> 6;
    int quad = lane >> 4, l16 = lane & 15;
    int bm = blockIdx.y * 128, bn = blockIdx.x * 128;
    int wm = (wv >> 1) * 64,  wn = (wv & 1) * 64;

    f32x4 acc[4][4] = {};
    int srow = tid >> 2, scol = (tid & 3) * 8;

    for (int k0 = 0; k0 < 1024; k0 += 32) {
        #pragma unroll
        for (int s = 0; s < 2; ++s) {
            int row = s * 64 + srow;
            gl_lds16(&A[(size_t)(bm + row) * lda + k0 + scol], &As[(s * 256 + wv * 64) * 8]);
            gl_lds16(&Bt[(size_t)(bn + row) * 1024 + k0 + scol], &Bs[(s * 256 + wv * 64) * 8]);
        }
        __syncthreads();
        bf16x8 af[4], bfv[4];
        #pragma unroll
        for (int mi = 0; mi < 4; ++mi)
            af[mi] = *reinterpret_cast<const bf16x8*>(&As[(wm + mi * 16 + l16) * 32 + quad * 8]);
        #pragma unroll
        for (int ni = 0; ni < 4; ++ni)
            bfv[ni] = *reinterpret_cast<const bf16x8*>(&Bs[(wn + ni * 16 + l16) * 32 + quad * 8]);
        #pragma unroll
        for (int mi = 0; mi < 4; ++mi)
            #pragma unroll
            for (int ni = 0; ni < 4; ++ni)
                acc[mi][ni] = __builtin_amdgcn_mfma_f32_16x16x32_bf16(af[mi], bfv[ni], acc[mi][ni], 0, 0, 0);
        __syncthreads();
    }

    #pragma unroll
    for (int mi = 0; mi < 4; ++mi) {
        #pragma unroll
        for (int ni = 0; ni < 4; ++ni) {
            int col = bn + wn + ni * 16 + l16;
            float bsv = bias[col];
            int hh = col >> 6, d = col & 63;
            #pragma unroll
            for (int ri = 0; ri < 4; ++ri) {
                int row = bm + wm + mi * 16 + quad * 4 + ri;
                float val = (acc[mi][ni][ri] + bsv) * scale;
                unsigned short bv = f2bf(val);
                int b = row >> 12, t = row & 4095;
                int bh = b * 16 + hh;
                {   // branch 0 (always covered)
                    int slot = t >> 9, idx = t & 511;
                    size_t sbh = (size_t)(slot * 32 + bh);
                    if (isV) Vtg[(sbh * 64 + d) * 512 + idx] = bv;
                    else     dstQK[(sbh * 512 + idx) * 64 + d] = bv;
                }
                if (((t ^ hh) & 1) == 0) {   // branch 1
                    int slot = 8 + (t >> 10), idx = (t & 1023) >> 1;
                    size_t sbh = (size_t)(slot * 32 + bh);
                    if (isV) Vtg[(sbh * 64 + d) * 512 + idx] = bv;
                    else     dstQK[(sbh * 512 + idx) * 64 + d] = bv;
                }
                if (((t ^ hh) & 3) == 0) {   // branch 2
                    int slot = 12 + (t >> 11), idx = (t & 2047) >> 2;
                    size_t sbh = (size_t)(slot * 32 + bh);
                    if (isV) Vtg[(sbh * 64 + d) * 512 + idx] = bv;
                    else     dstQK[(sbh * 512 + idx) * 64 + d] = bv;
                }
            }
        }
    }
}

// ---------------- dilated attention: paired q-tiles, LDS-staged K/V, balanced grid ----------------
// grid (2 pairs, 14 slots, 32 bh), block 256. Block pq processes q-tiles {pq, 3-pq} of one
// 512-row gathered segment (equal work per block). K and V^T tiles are staged to LDS once per
// jt and shared by both q-tiles and all 4 waves. Vtg is pre-transposed in global, so V staging
// is a plain row copy (padded stride-72: 2-way bank aliasing = free). 2 barriers/jt.
// Fixed-base softmax (m=0; scores O(1)): P = exp2(S) with q pre-scaled by log2e; LSE = ln(l).
__global__ __launch_bounds__(256, 3) void k_attn(
    const unsigned short* __restrict__ Qg,
    const unsigned short* __restrict__ Kg,
    const unsigned short* __restrict__ Vtg,
    unsigned short* __restrict__ Og,
    float* __restrict__ Lg)
{
    __shared__ unsigned short Ks[64 * 72];
    __shared__ unsigned short Vs[64 * 72];      // [d][kcol] (pre-transposed in global)
    __shared__ unsigned short Ps[4][16 * 72];   // per-wave P buffer

    int tid  = threadIdx.x;
    int lane = tid & 63, wv = tid >> 6;
    int quad = lane >> 4, l16 = lane & 15;
    int pq = blockIdx.x, ys = blockIdx.y, bh = blockIdx.z;
    int jt_end = 2 * (3 - pq) + 1;    // 7 (pair 0,3) or 5 (pair 1,2)
    size_t sb = (size_t)(ys * 32 + bh) * (512 * 64);
    const unsigned short* qp = Qg + sb;
    const unsigned short* kp = Kg + sb;
    const unsigned short* vp = Vtg + sb;
    unsigned short* op = Og + sb;
    float* lp = Lg + (size_t)(ys * 32 + bh) * 512;
    unsigned short* pw = Ps[wv];

    int rw[2] = { pq * 128 + wv * 32, (3 - pq) * 128 + wv * 32 };

    // Q fragments for both q-tiles, direct from global (wave-private, read once)
    bf16x8 qf[2][2][2];
    #pragma unroll
    for (int qi = 0; qi < 2; ++qi)
        #pragma unroll
        for (int m16 = 0; m16 < 2; ++m16)
            #pragma unroll
            for (int kk = 0; kk < 2; ++kk)
                qf[qi][m16][kk] = *reinterpret_cast<const bf16x8*>(
                    &qp[(size_t)(rw[qi] + m16 * 16 + l16) * 64 + kk * 32 + quad * 8]);

    f32x4 acc[2][2][4] = {};
    float l4[2][2][4] = {};

    for (int jt = 0; jt <= jt_end; ++jt) {
        __syncthreads();   // previous-iter K/V reads complete before overwrite
        #pragma unroll
        for (int s = 0; s < 2; ++s) {
            int e = s * 256 + tid;
            int row = e >> 3, c8 = (e & 7) * 8;
            *reinterpret_cast<uint4*>(&Ks[row * 72 + c8]) =
                *reinterpret_cast<const uint4*>(&kp[(size_t)(jt * 64 + row) * 64 + c8]);
            *reinterpret_cast<uint4*>(&Vs[row * 72 + c8]) =
                *reinterpret_cast<const uint4*>(&vp[(size_t)row * 512 + jt * 64 + c8]);
        }
        __syncthreads();

        #pragma unroll
        for (int qi = 0; qi < 2; ++qi) {
            #pragma unroll
            for (int m16 = 0; m16 < 2; ++m16) {
                int rowbase = rw[qi] + m16 * 16;
                if (jt * 64 > rowbase + 15) continue;   // fully masked (wave-uniform)

                // S = Q K^T (C-layout: row=quad*4+ri, col=nt*16+l16)
                f32x4 sacc[4];
                #pragma unroll
                for (int nt = 0; nt < 4; ++nt) {
                    bf16x8 b0 = *reinterpret_cast<const bf16x8*>(&Ks[(nt * 16 + l16) * 72 + quad * 8]);
                    bf16x8 b1 = *reinterpret_cast<const bf16x8*>(&Ks[(nt * 16 + l16) * 72 + 32 + quad * 8]);
                    f32x4 s4 = {};
                    s4 = __builtin_amdgcn_mfma_f32_16x16x32_bf16(qf[qi][m16][0], b0, s4, 0, 0, 0);
                    s4 = __builtin_amdgcn_mfma_f32_16x16x32_bf16(qf[qi][m16][1], b1, s4, 0, 0, 0);
                    sacc[nt] = s4;
                }
                if (jt * 64 + 63 > rowbase) {   // diagonal tile: causal mask
                    #pragma unroll
                    for (int nt = 0; nt < 4; ++nt)
                        #pragma unroll
                        for (int ri = 0; ri < 4; ++ri) {
                            int kj = jt * 64 + nt * 16 + l16, qi2 = rowbase + quad * 4 + ri;
                            if (kj > qi2) sacc[nt][ri] = -1e30f;
                        }
                }
                // P = exp2(S); per-lane partial row sums (single reduction after loop)
                #pragma unroll
                for (int nt = 0; nt < 4; ++nt)
                    #pragma unroll
                    for (int ri = 0; ri < 4; ++ri) {
                        float p = exp2f(sacc[nt][ri]);
                        sacc[nt][ri] = p;
                        l4[qi][m16][ri] += p;
                    }
                // P -> wave-private LDS (quad-rotated nt: 2-way aliasing only)
                #pragma unroll
                for (int j = 0; j < 4; ++j) {
                    int nt = (j + quad) & 3;
                    #pragma unroll
                    for (int ri = 0; ri < 4; ++ri)
                        pw[(quad * 4 + ri) * 72 + nt * 16 + l16] = f2bf(sacc[nt][ri]);
                }
                bf16x8 pf[2];
                #pragma unroll
                for (int kk = 0; kk < 2; ++kk)
                    pf[kk] = *reinterpret_cast<const bf16x8*>(&pw[l16 * 72 + kk * 32 + quad * 8]);
                // O += P V
                #pragma unroll
                for (int dt = 0; dt < 4; ++dt) {
                    bf16x8 v0 = *reinterpret_cast<const bf16x8*>(&Vs[(dt * 16 + l16) * 72 + quad * 8]);
                    bf16x8 v1 = *reinterpret_cast<const bf16x8*>(&Vs[(dt * 16 + l16) * 72 + 32 + quad * 8]);
                    f32x4 a4 = acc[qi][m16][dt];
                    a4 = __builtin_amdgcn_mfma_f32_16x16x32_bf16(pf[0], v0, a4, 0, 0, 0);
                    a4 = __builtin_amdgcn_mfma_f32_16x16x32_bf16(pf[1], v1, a4, 0, 0, 0);
                    acc[qi][m16][dt] = a4;
                }
            }
        }
    }

    // single l-reduction across the 16-lane row group, then write O and LSE
    #pragma unroll
    for (int qi = 0; qi < 2; ++qi)
        #pragma unroll
        for (int m16 = 0; m16 < 2; ++m16) {
            #pragma unroll
            for (int ri = 0; ri < 4; ++ri) {
                float l = l4[qi][m16][ri];
                l += __shfl_xor(l, 1);
                l += __shfl_xor(l, 2);
                l += __shfl_xor(l, 4);
                l += __shfl_xor(l, 8);
                l4[qi][m16][ri] = l;
            }
            #pragma unroll
            for (int dt = 0; dt < 4; ++dt)
                #pragma unroll
                for (int ri = 0; ri < 4; ++ri) {
                    int row = rw[qi] + m16 * 16 + quad * 4 + ri;
                    op[(size_t)row * 64 + dt * 16 + l16] = f2bf(acc[qi][m16][dt][ri] / l4[qi][m16][ri]);
                }
            if (l16 == 0) {
                #pragma unroll
                for (int ri = 0; ri < 4; ++ri) {
                    int row = rw[qi] + m16 * 16 + quad * 4 + ri;
                    lp[row] = __logf(l4[qi][m16][ri]);
                }
            }
        }
}

// ---------------- combine branches via LSE weights (coverage computed analytically) ----------------
__global__ void k_combine(const unsigned short* __restrict__ Og,
                          const float* __restrict__ Lg,
                          unsigned short* __restrict__ yb)
{
    int g   = blockIdx.x * blockDim.x + threadIdx.x; // 131072 rows * 8 parts
    int row = g >> 3;
    int d0  = (g & 7) * 8;
    int bh = row >> 12, t = row & 4095;
    int b = bh >> 4, h = bh & 15;

    int slot0 = t >> 9,         idx0 = t & 511;
    int slot1 = 8 + (t >> 10),  idx1 = (t & 1023) >> 1;
    int slot2 = 12 + (t >> 11), idx2 = (t & 2047) >> 2;
    size_t r0 = (size_t)(slot0 * 32 + bh) * 512 + idx0;
    size_t r1 = (size_t)(slot1 * 32 + bh) * 512 + idx1;
    size_t r2 = (size_t)(slot2 * 32 + bh) * 512 + idx2;
    bool c1 = ((t ^ h) & 1) == 0;
    bool c2 = ((t ^ h) & 3) == 0;

    float L0 = Lg[r0];
    float L1 = c1 ? Lg[r1] : -1e30f;
    float L2 = c2 ? Lg[r2] : -1e30f;
    float m  = fmaxf(L0, fmaxf(L1, L2));
    float w0 = __expf(L0 - m), w1 = __expf(L1 - m), w2 = __expf(L2 - m);
    float inv = 1.f / (w0 + w1 + w2);

    uint4 v0 = *reinterpret_cast<const uint4*>(&Og[r0 * 64 + d0]);
    uint4 v1 = *reinterpret_cast<const uint4*>(&Og[r1 * 64 + d0]);
    uint4 v2 = *reinterpret_cast<const uint4*>(&Og[r2 * 64 + d0]);
    const unsigned short* p0 = reinterpret_cast<const unsigned short*>(&v0);
    const unsigned short* p1 = reinterpret_cast<const unsigned short*>(&v1);
    const unsigned short* p2 = reinterpret_cast<const unsigned short*>(&v2);
    unsigned short o[8];
    #pragma unroll
    for (int u = 0; u < 8; ++u)
        o[u] = f2bf((w0 * bf2f(p0[u]) + w1 * bf2f(p1[u]) + w2 * bf2f(p2[u])) * inv);
    size_t yidx = (((size_t)b * 4096 + t) * 1024) + (size_t)h * 64 + d0;
    *reinterpret_cast<uint4*>(&yb[yidx]) = *reinterpret_cast<const uint4*>(o);
}

extern "C" void kernel_launch(void* const* d_in, const int* in_sizes, int n_in,
                              void* d_out, int out_size, void* d_ws, size_t ws_size,
                              hipStream_t stream)
{
    const float* x        = (const float*)d_in[0];
    const float* c_attn_w = (const float*)d_in[1];
    const float* c_attn_b = (const float*)d_in[2];
    const float* q_w      = (const float*)d_in[3];
    const float* q_b      = (const float*)d_in[4];
    const float* k_w      = (const float*)d_in[5];
    const float* k_b      = (const float*)d_in[6];
    const float* v_w      = (const float*)d_in[7];
    const float* v_b      = (const float*)d_in[8];
    const float* o_w      = (const float*)d_in[9];
    const float* o_b      = (const float*)d_in[10];

    char* ws = (char*)d_ws;
    size_t off = 0;
    auto alloc = [&](size_t bytes) -> char* {
        char* p = ws + off; off += (bytes + 255) & ~(size_t)255; return p;
    };
    const size_t GSZ = 14ull * 32 * 512 * 64;   // gathered tensor elements
    unsigned short* xb    = (unsigned short*)alloc(8192ull * 1024 * 2);
    unsigned short* wqkvT = (unsigned short*)alloc(3072ull * 1024 * 2);
    unsigned short* wqT   = (unsigned short*)alloc(1024ull * 1024 * 2);   // wq/wk/wv contiguous
    unsigned short* wkT   = (unsigned short*)alloc(1024ull * 1024 * 2);
    unsigned short* wvT   = (unsigned short*)alloc(1024ull * 1024 * 2);
    unsigned short* woT   = (unsigned short*)alloc(1024ull * 1024 * 2);
    unsigned short* qkvb  = (unsigned short*)alloc(8192ull * 3072 * 2);
    unsigned short* Qg    = (unsigned short*)alloc(GSZ * 2);
    unsigned short* Kg    = (unsigned short*)alloc(GSZ * 2);
    unsigned short* Vtg   = (unsigned short*)alloc(GSZ * 2);
    float*          Lg    = (float*)alloc(14ull * 32 * 512 * 4);
    unsigned short* Og    = qkvb;  // alias: qkvb dead after k_gemm3
    unsigned short* yb    = xb;    // alias: xb dead after qkv GEMM
    (void)wkT; (void)wvT;

    // 1. cast x to bf16
    k_cast<<<(8192 * 1024) / 1024, 256, 0, stream>>>(x, xb, 8192 * 1024);
    // 2. transpose-cast weights to [N][K] bf16
    k_transpose_cast<<<dim3(3072 / 32, 1024 / 32), dim3(32, 8), 0, stream>>>(c_attn_w, wqkvT, 1024, 3072);
    k_transpose_cast<<<dim3(32, 32), dim3(32, 8), 0, stream>>>(q_w, wqT, 1024, 1024);
    k_transpose_cast<<<dim3(32, 32), dim3(32, 8), 0, stream>>>(k_w, wkT, 1024, 1024);
    k_transpose_cast<<<dim3(32, 32), dim3(32, 8), 0, stream>>>(v_w, wvT, 1024, 1024);
    k_transpose_cast<<<dim3(32, 32), dim3(32, 8), 0, stream>>>(o_w, woT, 1024, 1024);
    // 3. qkv = x @ c_attn_w + b
    k_gemm<<<dim3(24, 64), 256, 0, stream>>>(xb, 1024, wqkvT, 1024, c_attn_b, qkvb, 8192, 3072, 1024, 0, 1.f);
    // 4. fused q/k/v projections -> gathered per-branch layouts (q pre-scaled by D^-0.5*log2e)
    k_gemm3<<<dim3(8, 64, 3), 256, 0, stream>>>(qkvb, 3072, wqT, q_b, k_b, v_b, Qg, Kg, Vtg);
    // 5. attention: paired q-tiles, balanced grid
    k_attn<<<dim3(2, 14, 32), 256, 0, stream>>>(Qg, Kg, Vtg, Og, Lg);
    // 6. combine branches -> y [B,T,C] bf16
    k_combine<<<4096, 256, 0, stream>>>(Og, Lg, yb);
    // 7. out = y @ o_w + o_b (fp32)
    k_gemm<<<dim3(8, 64), 256, 0, stream>>>(yb, 1024, woT, 1024, o_b, d_out, 8192, 1024, 1024, 2, 1.f);
}

// Round 8
// 501.484 us; speedup vs baseline: 1.3244x; 1.0110x over previous
//
#include <hip/hip_runtime.h>
#include <hip/hip_bf16.h>

typedef __bf16 bf16x8 __attribute__((ext_vector_type(8)));
typedef float  f32x4  __attribute__((ext_vector_type(4)));

__device__ __forceinline__ unsigned short f2bf(float f) {
    union { float f; unsigned int u; } v; v.f = f;
    return (unsigned short)((v.u + 0x8000u) >> 16);   // round-half-up: 2 VALU
}
__device__ __forceinline__ float bf2f(unsigned short h) {
    union { unsigned int u; float f; } v; v.u = ((unsigned int)h) << 16;
    return v.f;
}

typedef __attribute__((address_space(3))) unsigned int lds_u32_t;
typedef const __attribute__((address_space(1))) unsigned int glb_u32_t;
__device__ __forceinline__ void gl_lds16(const void* g, void* l) {
    __builtin_amdgcn_global_load_lds((glb_u32_t*)g, (lds_u32_t*)l, 16, 0, 0);
}

// ---------------- cast fp32 -> bf16 (flat) ----------------
__global__ void k_cast(const float* __restrict__ in, unsigned short* __restrict__ out, int n) {
    int i = (blockIdx.x * blockDim.x + threadIdx.x) * 4;
    if (i + 3 < n) {
        float4 v = *reinterpret_cast<const float4*>(in + i);
        ushort4 o;
        o.x = f2bf(v.x); o.y = f2bf(v.y); o.z = f2bf(v.z); o.w = f2bf(v.w);
        *reinterpret_cast<ushort4*>(out + i) = o;
    }
}

// ---------------- 4x transpose+cast 1024x1024: [K][N] f32 -> [N][K] bf16 ----------------
__global__ void k_transpose4(const float* __restrict__ s0, const float* __restrict__ s1,
                             const float* __restrict__ s2, const float* __restrict__ s3,
                             unsigned short* __restrict__ d0, unsigned short* __restrict__ d1,
                             unsigned short* __restrict__ d2, unsigned short* __restrict__ d3) {
    __shared__ float tile[32][33];
    int z = blockIdx.z;
    const float* in = (z == 0) ? s0 : (z == 1) ? s1 : (z == 2) ? s2 : s3;
    unsigned short* out = (z == 0) ? d0 : (z == 1) ? d1 : (z == 2) ? d2 : d3;
    int n0 = blockIdx.x * 32, k0 = blockIdx.y * 32;
    int tx = threadIdx.x, ty = threadIdx.y; // block (32,8)
    #pragma unroll
    for (int i = 0; i < 4; ++i)
        tile[ty + i * 8][tx] = in[(size_t)(k0 + ty + i * 8) * 1024 + n0 + tx];
    __syncthreads();
    #pragma unroll
    for (int i = 0; i < 4; ++i)
        out[(size_t)(n0 + ty + i * 8) * 1024 + k0 + tx] = f2bf(tile[tx][ty + i * 8]);
}

// ---------------- bf16 MFMA GEMM (m97 structure): out = A[M,K] * Bt[N,K]^T + bias ----------------
// mode 0: out bf16 row-major [M,N];  mode 2: out fp32 row-major [M,N]
__global__ __launch_bounds__(256) void k_gemm(
    const unsigned short* __restrict__ A, int lda,
    const unsigned short* __restrict__ Bt, int ldb,
    const float* __restrict__ bias,
    void* __restrict__ out,
    int M, int N, int K, int mode, float scale)
{
    __shared__ unsigned short As[128 * 32];
    __shared__ unsigned short Bs[128 * 32];
    int tid  = threadIdx.x;
    int lane = tid & 63, wv = tid >> 6;
    int quad = lane >> 4, l16 = lane & 15;
    int bm = blockIdx.y * 128, bn = blockIdx.x * 128;
    int wm = (wv >> 1) * 64,  wn = (wv & 1) * 64;

    f32x4 acc[4][4] = {};
    int srow = tid >> 2, scol = (tid & 3) * 8;

    for (int k0 = 0; k0 < K; k0 += 32) {
        #pragma unroll
        for (int s = 0; s < 2; ++s) {
            int row = s * 64 + srow;
            gl_lds16(&A[(size_t)(bm + row) * lda + k0 + scol], &As[(s * 256 + wv * 64) * 8]);
            gl_lds16(&Bt[(size_t)(bn + row) * ldb + k0 + scol], &Bs[(s * 256 + wv * 64) * 8]);
        }
        __syncthreads();
        bf16x8 af[4], bfv[4];
        #pragma unroll
        for (int mi = 0; mi < 4; ++mi)
            af[mi] = *reinterpret_cast<const bf16x8*>(&As[(wm + mi * 16 + l16) * 32 + quad * 8]);
        #pragma unroll
        for (int ni = 0; ni < 4; ++ni)
            bfv[ni] = *reinterpret_cast<const bf16x8*>(&Bs[(wn + ni * 16 + l16) * 32 + quad * 8]);
        #pragma unroll
        for (int mi = 0; mi < 4; ++mi)
            #pragma unroll
            for (int ni = 0; ni < 4; ++ni)
                acc[mi][ni] = __builtin_amdgcn_mfma_f32_16x16x32_bf16(af[mi], bfv[ni], acc[mi][ni], 0, 0, 0);
        __syncthreads();
    }

    #pragma unroll
    for (int mi = 0; mi < 4; ++mi) {
        #pragma unroll
        for (int ni = 0; ni < 4; ++ni) {
            int col = bn + wn + ni * 16 + l16;
            float bsv = bias[col];
            #pragma unroll
            for (int ri = 0; ri < 4; ++ri) {
                int row = bm + wm + mi * 16 + quad * 4 + ri;
                float val = (acc[mi][ni][ri] + bsv) * scale;
                if (mode == 0)
                    reinterpret_cast<unsigned short*>(out)[(size_t)row * N + col] = f2bf(val);
                else
                    reinterpret_cast<float*>(out)[(size_t)row * N + col] = val;
            }
        }
    }
}

// ---------------- weight fold: W_eff^T[z] = wT[z] @ WcB[:, z*1024 +: 1024]  (bf16 out) ----------------
// wT3: 3 contiguous [1024 out][1024 c] bf16 (q_w^T,k_w^T,v_w^T); WcB: [1024 in][3072 c-out] bf16.
// out[m=out][j=in] = sum_c wT[m][c] * WcB[j][z*1024+c].  z==0 scaled by 0.125*log2e.
__global__ __launch_bounds__(256) void k_foldw(
    const unsigned short* __restrict__ wT3,
    const unsigned short* __restrict__ WcB,
    unsigned short* __restrict__ Weff)
{
    __shared__ unsigned short As[128 * 32];
    __shared__ unsigned short Bs[128 * 32];
    int z = blockIdx.z;
    const unsigned short* A  = wT3 + (size_t)z * 1024 * 1024;
    const unsigned short* Bt = WcB + z * 1024;
    unsigned short* out = Weff + (size_t)z * 1024 * 1024;
    float scale = (z == 0) ? 0.1803368801f : 1.f;

    int tid  = threadIdx.x;
    int lane = tid & 63, wv = tid >> 6;
    int quad = lane >> 4, l16 = lane & 15;
    int bm = blockIdx.y * 128, bn = blockIdx.x * 128;
    int wm = (wv >> 1) * 64,  wn = (wv & 1) * 64;

    f32x4 acc[4][4] = {};
    int srow = tid >> 2, scol = (tid & 3) * 8;

    for (int k0 = 0; k0 < 1024; k0 += 32) {
        #pragma unroll
        for (int s = 0; s < 2; ++s) {
            int row = s * 64 + srow;
            gl_lds16(&A[(size_t)(bm + row) * 1024 + k0 + scol], &As[(s * 256 + wv * 64) * 8]);
            gl_lds16(&Bt[(size_t)(bn + row) * 3072 + k0 + scol], &Bs[(s * 256 + wv * 64) * 8]);
        }
        __syncthreads();
        bf16x8 af[4], bfv[4];
        #pragma unroll
        for (int mi = 0; mi < 4; ++mi)
            af[mi] = *reinterpret_cast<const bf16x8*>(&As[(wm + mi * 16 + l16) * 32 + quad * 8]);
        #pragma unroll
        for (int ni = 0; ni < 4; ++ni)
            bfv[ni] = *reinterpret_cast<const bf16x8*>(&Bs[(wn + ni * 16 + l16) * 32 + quad * 8]);
        #pragma unroll
        for (int mi = 0; mi < 4; ++mi)
            #pragma unroll
            for (int ni = 0; ni < 4; ++ni)
                acc[mi][ni] = __builtin_amdgcn_mfma_f32_16x16x32_bf16(af[mi], bfv[ni], acc[mi][ni], 0, 0, 0);
        __syncthreads();
    }

    #pragma unroll
    for (int mi = 0; mi < 4; ++mi)
        #pragma unroll
        for (int ni = 0; ni < 4; ++ni) {
            int col = bn + wn + ni * 16 + l16;
            #pragma unroll
            for (int ri = 0; ri < 4; ++ri) {
                int row = bm + wm + mi * 16 + quad * 4 + ri;
                out[(size_t)row * 1024 + col] = f2bf(acc[mi][ni][ri] * scale);
            }
        }
}

// ---------------- bias fold: b_eff[z][n] = scale_z*(sum_c bc[z*1024+c]*w_z[c][n] + b2_z[n]) ----------------
__global__ void k_foldb(const unsigned short* __restrict__ wT3, const float* __restrict__ bc,
                        const float* __restrict__ qb, const float* __restrict__ kb,
                        const float* __restrict__ vb, float* __restrict__ beff)
{
    int id = blockIdx.x * blockDim.x + threadIdx.x;  // 0..3071
    int z = id >> 10, n = id & 1023;
    const unsigned short* row = wT3 + (size_t)z * 1024 * 1024 + (size_t)n * 1024;
    const float* b2 = (z == 0) ? qb : (z == 1) ? kb : vb;
    float s = 0.f;
    for (int c = 0; c < 1024; ++c) s += bc[z * 1024 + c] * bf2f(row[c]);
    s += b2[n];
    if (z == 0) s *= 0.1803368801f;
    beff[id] = s;
}

// ---------------- fused projections: x @ W_eff[z] + b_eff[z] -> gathered layouts ----------------
// Qg/Kg: [slot14][bh32][idx512][d64]; Vtg: [slot14][bh32][d64][idx512] (V via LDS transpose, coalesced)
__global__ __launch_bounds__(256) void k_gemm3(
    const unsigned short* __restrict__ A,      // xb [8192][1024]
    const unsigned short* __restrict__ Weff,   // [3][1024][1024]
    const float* __restrict__ beff,            // [3][1024]
    unsigned short* __restrict__ Qg, unsigned short* __restrict__ Kg,
    unsigned short* __restrict__ Vtg)
{
    __shared__ unsigned short smem[8320];      // As(4096)+Bs(4096) in-loop; Vt[64][130] in epilogue
    unsigned short* As = smem;
    unsigned short* Bs = smem + 4096;
    int z = blockIdx.z;
    const unsigned short* Bt = Weff + (size_t)z * 1024 * 1024;
    const float* bias = beff + z * 1024;

    int tid  = threadIdx.x;
    int lane = tid & 63, wv = tid >> 6;
    int quad = lane >> 4, l16 = lane & 15;
    int bm = blockIdx.y * 128, bn = blockIdx.x * 128;
    int wm = (wv >> 1) * 64,  wn = (wv & 1) * 64;

    f32x4 acc[4][4] = {};
    int srow = tid >> 2, scol = (tid & 3) * 8;

    for (int k0 = 0; k0 < 1024; k0 += 32) {
        #pragma unroll
        for (int s = 0; s < 2; ++s) {
            int row = s * 64 + srow;
            gl_lds16(&A[(size_t)(bm + row) * 1024 + k0 + scol], &As[(s * 256 + wv * 64) * 8]);
            gl_lds16(&Bt[(size_t)(bn + row) * 1024 + k0 + scol], &Bs[(s * 256 + wv * 64) * 8]);
        }
        __syncthreads();
        bf16x8 af[4], bfv[4];
        #pragma unroll
        for (int mi = 0; mi < 4; ++mi)
            af[mi] = *reinterpret_cast<const bf16x8*>(&As[(wm + mi * 16 + l16) * 32 + quad * 8]);
        #pragma unroll
        for (int ni = 0; ni < 4; ++ni)
            bfv[ni] = *reinterpret_cast<const bf16x8*>(&Bs[(wn + ni * 16 + l16) * 32 + quad * 8]);
        #pragma unroll
        for (int mi = 0; mi < 4; ++mi)
            #pragma unroll
            for (int ni = 0; ni < 4; ++ni)
                acc[mi][ni] = __builtin_amdgcn_mfma_f32_16x16x32_bf16(af[mi], bfv[ni], acc[mi][ni], 0, 0, 0);
        __syncthreads();
    }

    if (z < 2) {
        // Q/K scatter epilogue ([idx][d] rows; 32B runs per quad)
        unsigned short* dst = (z == 0) ? Qg : Kg;
        #pragma unroll
        for (int mi = 0; mi < 4; ++mi)
            #pragma unroll
            for (int ni = 0; ni < 4; ++ni) {
                int col = bn + wn + ni * 16 + l16;
                float bsv = bias[col];
                int hh = col >> 6, d = col & 63;
                #pragma unroll
                for (int ri = 0; ri < 4; ++ri) {
                    int row = bm + wm + mi * 16 + quad * 4 + ri;
                    unsigned short bv = f2bf(acc[mi][ni][ri] + bsv);
                    int b = row >> 12, t = row & 4095;
                    int bh = b * 16 + hh;
                    { int slot = t >> 9, idx = t & 511;
                      dst[((size_t)(slot * 32 + bh) * 512 + idx) * 64 + d] = bv; }
                    if (((t ^ hh) & 1) == 0) {
                        int slot = 8 + (t >> 10), idx = (t & 1023) >> 1;
                        dst[((size_t)(slot * 32 + bh) * 512 + idx) * 64 + d] = bv;
                    }
                    if (((t ^ hh) & 3) == 0) {
                        int slot = 12 + (t >> 11), idx = (t & 2047) >> 2;
                        dst[((size_t)(slot * 32 + bh) * 512 + idx) * 64 + d] = bv;
                    }
                }
            }
    } else {
        // V: LDS-transpose each 64-col head half, then coalesced [d][idx] runs per branch
        unsigned short* Vt = smem;            // [64 d][130]
        int b = bm >> 12, t0 = bm & 4095;
        #pragma unroll
        for (int half = 0; half < 2; ++half) {
            if ((wn >> 6) == half) {
                #pragma unroll
                for (int mi = 0; mi < 4; ++mi)
                    #pragma unroll
                    for (int ni = 0; ni < 4; ++ni) {
                        int col = bn + wn + ni * 16 + l16;
                        float bsv = bias[col];
                        int din = ni * 16 + l16;
                        #pragma unroll
                        for (int ri = 0; ri < 4; ++ri) {
                            int rowt = wm + mi * 16 + quad * 4 + ri;
                            Vt[din * 130 + rowt] = f2bf(acc[mi][ni][ri] + bsv);
                        }
                    }
            }
            __syncthreads();
            int d = tid >> 2, part = tid & 3;
            int h_glob = (bn >> 6) + half;
            int bh = b * 16 + h_glob;
            const unsigned short* lrow = &Vt[d * 130];
            {   // branch 0: 128 contiguous idx
                int slot = t0 >> 9;
                size_t dst = ((size_t)(slot * 32 + bh) * 64 + d) * 512 + (t0 & 511) + part * 32;
                unsigned short buf[32];
                #pragma unroll
                for (int j = 0; j < 32; ++j) buf[j] = lrow[part * 32 + j];
                #pragma unroll
                for (int j = 0; j < 4; ++j)
                    *reinterpret_cast<uint4*>(&Vtg[dst + j * 8]) = reinterpret_cast<const uint4*>(buf)[j];
            }
            {   // branch 1: every 2nd t (parity h), 64 contiguous idx
                int j0 = h_glob & 1;
                int slot = 8 + (t0 >> 10);
                size_t dst = ((size_t)(slot * 32 + bh) * 64 + d) * 512 + ((t0 & 1023) >> 1) + part * 16;
                unsigned short buf[16];
                #pragma unroll
                for (int j = 0; j < 16; ++j) buf[j] = lrow[j0 + 2 * (part * 16 + j)];
                #pragma unroll
                for (int j = 0; j < 2; ++j)
                    *reinterpret_cast<uint4*>(&Vtg[dst + j * 8]) = reinterpret_cast<const uint4*>(buf)[j];
            }
            {   // branch 2: every 4th t, 32 contiguous idx
                int j0 = h_glob & 3;
                int slot = 12 + (t0 >> 11);
                size_t dst = ((size_t)(slot * 32 + bh) * 64 + d) * 512 + ((t0 & 2047) >> 2) + part * 8;
                unsigned short buf[8];
                #pragma unroll
                for (int j = 0; j < 8; ++j) buf[j] = lrow[j0 + 4 * (part * 8 + j)];
                *reinterpret_cast<uint4*>(&Vtg[dst]) = *reinterpret_cast<const uint4*>(buf);
            }
            __syncthreads();
        }
    }
}

// ---------------- dilated attention: paired q-tiles, LDS K/V, 5 blocks/CU ----------------
__global__ __launch_bounds__(256, 5) void k_attn(
    const unsigned short* __restrict__ Qg,
    const unsigned short* __restrict__ Kg,
    const unsigned short* __restrict__ Vtg,
    unsigned short* __restrict__ Og,
    float* __restrict__ Lg)
{
    __shared__ unsigned short Ks[64 * 72];
    __shared__ unsigned short Vs[64 * 72];      // [d][kcol] (pre-transposed in global)
    __shared__ unsigned short Ps[4][16 * 72];   // per-wave P buffer

    int tid  = threadIdx.x;
    int lane = tid & 63, wv = tid >> 6;
    int quad = lane >> 4, l16 = lane & 15;
    int pq = blockIdx.x, ys = blockIdx.y, bh = blockIdx.z;
    int jt_end = 2 * (3 - pq) + 1;    // 7 (pair 0,3) or 5 (pair 1,2)
    size_t sb = (size_t)(ys * 32 + bh) * (512 * 64);
    const unsigned short* qp = Qg + sb;
    const unsigned short* kp = Kg + sb;
    const unsigned short* vp = Vtg + sb;
    unsigned short* op = Og + sb;
    float* lp = Lg + (size_t)(ys * 32 + bh) * 512;
    unsigned short* pw = Ps[wv];

    int rw[2] = { pq * 128 + wv * 32, (3 - pq) * 128 + wv * 32 };

    bf16x8 qf[2][2][2];
    #pragma unroll
    for (int qi = 0; qi < 2; ++qi)
        #pragma unroll
        for (int m16 = 0; m16 < 2; ++m16)
            #pragma unroll
            for (int kk = 0; kk < 2; ++kk)
                qf[qi][m16][kk] = *reinterpret_cast<const bf16x8*>(
                    &qp[(size_t)(rw[qi] + m16 * 16 + l16) * 64 + kk * 32 + quad * 8]);

    f32x4 acc[2][2][4] = {};
    float l4[2][2][4] = {};

    for (int jt = 0; jt <= jt_end; ++jt) {
        __syncthreads();
        #pragma unroll
        for (int s = 0; s < 2; ++s) {
            int e = s * 256 + tid;
            int row = e >> 3, c8 = (e & 7) * 8;
            *reinterpret_cast<uint4*>(&Ks[row * 72 + c8]) =
                *reinterpret_cast<const uint4*>(&kp[(size_t)(jt * 64 + row) * 64 + c8]);
            *reinterpret_cast<uint4*>(&Vs[row * 72 + c8]) =
                *reinterpret_cast<const uint4*>(&vp[(size_t)row * 512 + jt * 64 + c8]);
        }
        __syncthreads();

        #pragma unroll
        for (int qi = 0; qi < 2; ++qi) {
            #pragma unroll
            for (int m16 = 0; m16 < 2; ++m16) {
                int rowbase = rw[qi] + m16 * 16;
                if (jt * 64 > rowbase + 15) continue;

                f32x4 sacc[4];
                #pragma unroll
                for (int nt = 0; nt < 4; ++nt) {
                    bf16x8 b0 = *reinterpret_cast<const bf16x8*>(&Ks[(nt * 16 + l16) * 72 + quad * 8]);
                    bf16x8 b1 = *reinterpret_cast<const bf16x8*>(&Ks[(nt * 16 + l16) * 72 + 32 + quad * 8]);
                    f32x4 s4 = {};
                    s4 = __builtin_amdgcn_mfma_f32_16x16x32_bf16(qf[qi][m16][0], b0, s4, 0, 0, 0);
                    s4 = __builtin_amdgcn_mfma_f32_16x16x32_bf16(qf[qi][m16][1], b1, s4, 0, 0, 0);
                    sacc[nt] = s4;
                }
                if (jt * 64 + 63 > rowbase) {
                    #pragma unroll
                    for (int nt = 0; nt < 4; ++nt)
                        #pragma unroll
                        for (int ri = 0; ri < 4; ++ri) {
                            int kj = jt * 64 + nt * 16 + l16, qi2 = rowbase + quad * 4 + ri;
                            if (kj > qi2) sacc[nt][ri] = -1e30f;
                        }
                }
                #pragma unroll
                for (int nt = 0; nt < 4; ++nt)
                    #pragma unroll
                    for (int ri = 0; ri < 4; ++ri) {
                        float p = exp2f(sacc[nt][ri]);
                        sacc[nt][ri] = p;
                        l4[qi][m16][ri] += p;
                    }
                #pragma unroll
                for (int j = 0; j < 4; ++j) {
                    int nt = (j + quad) & 3;
                    #pragma unroll
                    for (int ri = 0; ri < 4; ++ri)
                        pw[(quad * 4 + ri) * 72 + nt * 16 + l16] = f2bf(sacc[nt][ri]);
                }
                bf16x8 pf[2];
                #pragma unroll
                for (int kk = 0; kk < 2; ++kk)
                    pf[kk] = *reinterpret_cast<const bf16x8*>(&pw[l16 * 72 + kk * 32 + quad * 8]);
                #pragma unroll
                for (int dt = 0; dt < 4; ++dt) {
                    bf16x8 v0 = *reinterpret_cast<const bf16x8*>(&Vs[(dt * 16 + l16) * 72 + quad * 8]);
                    bf16x8 v1 = *reinterpret_cast<const bf16x8*>(&Vs[(dt * 16 + l16) * 72 + 32 + quad * 8]);
                    f32x4 a4 = acc[qi][m16][dt];
                    a4 = __builtin_amdgcn_mfma_f32_16x16x32_bf16(pf[0], v0, a4, 0, 0, 0);
                    a4 = __builtin_amdgcn_mfma_f32_16x16x32_bf16(pf[1], v1, a4, 0, 0, 0);
                    acc[qi][m16][dt] = a4;
                }
            }
        }
    }

    #pragma unroll
    for (int qi = 0; qi < 2; ++qi)
        #pragma unroll
        for (int m16 = 0; m16 < 2; ++m16) {
            #pragma unroll
            for (int ri = 0; ri < 4; ++ri) {
                float l = l4[qi][m16][ri];
                l += __shfl_xor(l, 1);
                l += __shfl_xor(l, 2);
                l += __shfl_xor(l, 4);
                l += __shfl_xor(l, 8);
                l4[qi][m16][ri] = l;
            }
            #pragma unroll
            for (int dt = 0; dt < 4; ++dt)
                #pragma unroll
                for (int ri = 0; ri < 4; ++ri) {
                    int row = rw[qi] + m16 * 16 + quad * 4 + ri;
                    op[(size_t)row * 64 + dt * 16 + l16] = f2bf(acc[qi][m16][dt][ri] / l4[qi][m16][ri]);
                }
            if (l16 == 0) {
                #pragma unroll
                for (int ri = 0; ri < 4; ++ri) {
                    int row = rw[qi] + m16 * 16 + quad * 4 + ri;
                    lp[row] = __logf(l4[qi][m16][ri]);
                }
            }
        }
}

// ---------------- combine branches via LSE weights ----------------
__global__ void k_combine(const unsigned short* __restrict__ Og,
                          const float* __restrict__ Lg,
                          unsigned short* __restrict__ yb)
{
    int g   = blockIdx.x * blockDim.x + threadIdx.x;
    int row = g >> 3;
    int d0  = (g & 7) * 8;
    int bh = row >> 12, t = row & 4095;
    int b = bh >> 4, h = bh & 15;

    int slot0 = t >> 9,         idx0 = t & 511;
    int slot1 = 8 + (t >> 10),  idx1 = (t & 1023) >> 1;
    int slot2 = 12 + (t >> 11), idx2 = (t & 2047) >> 2;
    size_t r0 = (size_t)(slot0 * 32 + bh) * 512 + idx0;
    size_t r1 = (size_t)(slot1 * 32 + bh) * 512 + idx1;
    size_t r2 = (size_t)(slot2 * 32 + bh) * 512 + idx2;
    bool c1 = ((t ^ h) & 1) == 0;
    bool c2 = ((t ^ h) & 3) == 0;

    float L0 = Lg[r0];
    float L1 = c1 ? Lg[r1] : -1e30f;
    float L2 = c2 ? Lg[r2] : -1e30f;
    float m  = fmaxf(L0, fmaxf(L1, L2));
    float w0 = __expf(L0 - m), w1 = __expf(L1 - m), w2 = __expf(L2 - m);
    float inv = 1.f / (w0 + w1 + w2);

    uint4 v0 = *reinterpret_cast<const uint4*>(&Og[r0 * 64 + d0]);
    uint4 v1 = *reinterpret_cast<const uint4*>(&Og[r1 * 64 + d0]);
    uint4 v2 = *reinterpret_cast<const uint4*>(&Og[r2 * 64 + d0]);
    const unsigned short* p0 = reinterpret_cast<const unsigned short*>(&v0);
    const unsigned short* p1 = reinterpret_cast<const unsigned short*>(&v1);
    const unsigned short* p2 = reinterpret_cast<const unsigned short*>(&v2);
    unsigned short o[8];
    #pragma unroll
    for (int u = 0; u < 8; ++u)
        o[u] = f2bf((w0 * bf2f(p0[u]) + w1 * bf2f(p1[u]) + w2 * bf2f(p2[u])) * inv);
    size_t yidx = (((size_t)b * 4096 + t) * 1024) + (size_t)h * 64 + d0;
    *reinterpret_cast<uint4*>(&yb[yidx]) = *reinterpret_cast<const uint4*>(o);
}

extern "C" void kernel_launch(void* const* d_in, const int* in_sizes, int n_in,
                              void* d_out, int out_size, void* d_ws, size_t ws_size,
                              hipStream_t stream)
{
    const float* x        = (const float*)d_in[0];
    const float* c_attn_w = (const float*)d_in[1];
    const float* c_attn_b = (const float*)d_in[2];
    const float* q_w      = (const float*)d_in[3];
    const float* q_b      = (const float*)d_in[4];
    const float* k_w      = (const float*)d_in[5];
    const float* k_b      = (const float*)d_in[6];
    const float* v_w      = (const float*)d_in[7];
    const float* v_b      = (const float*)d_in[8];
    const float* o_w      = (const float*)d_in[9];
    const float* o_b      = (const float*)d_in[10];

    char* ws = (char*)d_ws;
    size_t off = 0;
    auto alloc = [&](size_t bytes) -> char* {
        char* p = ws + off; off += (bytes + 255) & ~(size_t)255; return p;
    };
    const size_t GSZ = 14ull * 32 * 512 * 64;
    unsigned short* xb    = (unsigned short*)alloc(8192ull * 1024 * 2);
    unsigned short* WcB   = (unsigned short*)alloc(1024ull * 3072 * 2);   // c_attn_w bf16, untransposed
    unsigned short* wqT   = (unsigned short*)alloc(1024ull * 1024 * 2);   // q/k/v contiguous
    unsigned short* wkT   = (unsigned short*)alloc(1024ull * 1024 * 2);
    unsigned short* wvT   = (unsigned short*)alloc(1024ull * 1024 * 2);
    unsigned short* woT   = (unsigned short*)alloc(1024ull * 1024 * 2);
    unsigned short* Weff  = (unsigned short*)alloc(3ull * 1024 * 1024 * 2);
    float*          beff  = (float*)alloc(3ull * 1024 * 4);
    unsigned short* Qg    = (unsigned short*)alloc(GSZ * 2);
    unsigned short* Kg    = (unsigned short*)alloc(GSZ * 2);
    unsigned short* Vtg   = (unsigned short*)alloc(GSZ * 2);
    unsigned short* Og    = (unsigned short*)alloc(GSZ * 2);
    float*          Lg    = (float*)alloc(14ull * 32 * 512 * 4);
    unsigned short* yb    = xb;   // alias: xb dead after k_gemm3
    (void)wkT; (void)wvT;

    // 1. casts
    k_cast<<<(8192 * 1024) / 1024, 256, 0, stream>>>(x, xb, 8192 * 1024);
    k_cast<<<(1024 * 3072) / 1024, 256, 0, stream>>>(c_attn_w, WcB, 1024 * 3072);
    // 2. transpose-cast q/k/v/o weights (one dispatch)
    k_transpose4<<<dim3(32, 32, 4), dim3(32, 8), 0, stream>>>(q_w, k_w, v_w, o_w, wqT, wkT, wvT, woT);
    // 3. weight/bias folding: W_eff = Wc_part @ w, b_eff = bc_part @ w + b (q scaled by D^-0.5*log2e)
    k_foldw<<<dim3(8, 8, 3), 256, 0, stream>>>(wqT, WcB, Weff);
    k_foldb<<<12, 256, 0, stream>>>(wqT, c_attn_b, q_b, k_b, v_b, beff);
    // 4. fused projections: x -> gathered Q/K/V^T
    k_gemm3<<<dim3(8, 64, 3), 256, 0, stream>>>(xb, Weff, beff, Qg, Kg, Vtg);
    // 5. attention (paired q-tiles, 5 blocks/CU)
    k_attn<<<dim3(2, 14, 32), 256, 0, stream>>>(Qg, Kg, Vtg, Og, Lg);
    // 6. combine -> y
    k_combine<<<4096, 256, 0, stream>>>(Og, Lg, yb);
    // 7. out = y @ o_w + o_b (fp32)
    k_gemm<<<dim3(8, 64), 256, 0, stream>>>(yb, 1024, woT, 1024, o_b, d_out, 8192, 1024, 1024, 2, 1.f);
}

// Round 9
// 482.238 us; speedup vs baseline: 1.3772x; 1.0399x over previous
//
#include <hip/hip_runtime.h>
#include <hip/hip_bf16.h>

typedef __bf16 bf16x8 __attribute__((ext_vector_type(8)));
typedef float  f32x4  __attribute__((ext_vector_type(4)));

__device__ __forceinline__ unsigned short f2bf(float f) {
    union { float f; unsigned int u; } v; v.f = f;
    return (unsigned short)((v.u + 0x8000u) >> 16);   // round-half-up: 2 VALU
}
__device__ __forceinline__ float bf2f(unsigned short h) {
    union { unsigned int u; float f; } v; v.u = ((unsigned int)h) << 16;
    return v.f;
}

typedef __attribute__((address_space(3))) unsigned int lds_u32_t;
typedef const __attribute__((address_space(1))) unsigned int glb_u32_t;
__device__ __forceinline__ void gl_lds16(const void* g, void* l) {
    __builtin_amdgcn_global_load_lds((glb_u32_t*)g, (lds_u32_t*)l, 16, 0, 0);
}

// ---------------- cast fp32 -> bf16 (flat) ----------------
__global__ void k_cast(const float* __restrict__ in, unsigned short* __restrict__ out, int n) {
    int i = (blockIdx.x * blockDim.x + threadIdx.x) * 4;
    if (i + 3 < n) {
        float4 v = *reinterpret_cast<const float4*>(in + i);
        ushort4 o;
        o.x = f2bf(v.x); o.y = f2bf(v.y); o.z = f2bf(v.z); o.w = f2bf(v.w);
        *reinterpret_cast<ushort4*>(out + i) = o;
    }
}

// ---------------- 4x transpose+cast 1024x1024: [K][N] f32 -> [N][K] bf16 ----------------
__global__ void k_transpose4(const float* __restrict__ s0, const float* __restrict__ s1,
                             const float* __restrict__ s2, const float* __restrict__ s3,
                             unsigned short* __restrict__ d0, unsigned short* __restrict__ d1,
                             unsigned short* __restrict__ d2, unsigned short* __restrict__ d3) {
    __shared__ float tile[32][33];
    int z = blockIdx.z;
    const float* in = (z == 0) ? s0 : (z == 1) ? s1 : (z == 2) ? s2 : s3;
    unsigned short* out = (z == 0) ? d0 : (z == 1) ? d1 : (z == 2) ? d2 : d3;
    int n0 = blockIdx.x * 32, k0 = blockIdx.y * 32;
    int tx = threadIdx.x, ty = threadIdx.y; // block (32,8)
    #pragma unroll
    for (int i = 0; i < 4; ++i)
        tile[ty + i * 8][tx] = in[(size_t)(k0 + ty + i * 8) * 1024 + n0 + tx];
    __syncthreads();
    #pragma unroll
    for (int i = 0; i < 4; ++i)
        out[(size_t)(n0 + ty + i * 8) * 1024 + k0 + tx] = f2bf(tile[tx][ty + i * 8]);
}

// ---------------- bf16 MFMA GEMM (m97 structure): out = A[M,K] * Bt[N,K]^T + bias ----------------
// mode 0: out bf16 row-major [M,N];  mode 2: out fp32 row-major [M,N]
__global__ __launch_bounds__(256) void k_gemm(
    const unsigned short* __restrict__ A, int lda,
    const unsigned short* __restrict__ Bt, int ldb,
    const float* __restrict__ bias,
    void* __restrict__ out,
    int M, int N, int K, int mode, float scale)
{
    __shared__ unsigned short As[128 * 32];
    __shared__ unsigned short Bs[128 * 32];
    int tid  = threadIdx.x;
    int lane = tid & 63, wv = tid >> 6;
    int quad = lane >> 4, l16 = lane & 15;
    int bm = blockIdx.y * 128, bn = blockIdx.x * 128;
    int wm = (wv >> 1) * 64,  wn = (wv & 1) * 64;

    f32x4 acc[4][4] = {};
    int srow = tid >> 2, scol = (tid & 3) * 8;

    for (int k0 = 0; k0 < K; k0 += 32) {
        #pragma unroll
        for (int s = 0; s < 2; ++s) {
            int row = s * 64 + srow;
            gl_lds16(&A[(size_t)(bm + row) * lda + k0 + scol], &As[(s * 256 + wv * 64) * 8]);
            gl_lds16(&Bt[(size_t)(bn + row) * ldb + k0 + scol], &Bs[(s * 256 + wv * 64) * 8]);
        }
        __syncthreads();
        bf16x8 af[4], bfv[4];
        #pragma unroll
        for (int mi = 0; mi < 4; ++mi)
            af[mi] = *reinterpret_cast<const bf16x8*>(&As[(wm + mi * 16 + l16) * 32 + quad * 8]);
        #pragma unroll
        for (int ni = 0; ni < 4; ++ni)
            bfv[ni] = *reinterpret_cast<const bf16x8*>(&Bs[(wn + ni * 16 + l16) * 32 + quad * 8]);
        #pragma unroll
        for (int mi = 0; mi < 4; ++mi)
            #pragma unroll
            for (int ni = 0; ni < 4; ++ni)
                acc[mi][ni] = __builtin_amdgcn_mfma_f32_16x16x32_bf16(af[mi], bfv[ni], acc[mi][ni], 0, 0, 0);
        __syncthreads();
    }

    #pragma unroll
    for (int mi = 0; mi < 4; ++mi) {
        #pragma unroll
        for (int ni = 0; ni < 4; ++ni) {
            int col = bn + wn + ni * 16 + l16;
            float bsv = bias[col];
            #pragma unroll
            for (int ri = 0; ri < 4; ++ri) {
                int row = bm + wm + mi * 16 + quad * 4 + ri;
                float val = (acc[mi][ni][ri] + bsv) * scale;
                if (mode == 0)
                    reinterpret_cast<unsigned short*>(out)[(size_t)row * N + col] = f2bf(val);
                else
                    reinterpret_cast<float*>(out)[(size_t)row * N + col] = val;
            }
        }
    }
}

// ---------------- weight fold: W_eff^T[z] = wT[z] @ WcB[:, z*1024 +: 1024]  (bf16 out) ----------------
__global__ __launch_bounds__(256) void k_foldw(
    const unsigned short* __restrict__ wT3,
    const unsigned short* __restrict__ WcB,
    unsigned short* __restrict__ Weff)
{
    __shared__ unsigned short As[128 * 32];
    __shared__ unsigned short Bs[128 * 32];
    int z = blockIdx.z;
    const unsigned short* A  = wT3 + (size_t)z * 1024 * 1024;
    const unsigned short* Bt = WcB + z * 1024;
    unsigned short* out = Weff + (size_t)z * 1024 * 1024;
    float scale = (z == 0) ? 0.1803368801f : 1.f;

    int tid  = threadIdx.x;
    int lane = tid & 63, wv = tid >> 6;
    int quad = lane >> 4, l16 = lane & 15;
    int bm = blockIdx.y * 128, bn = blockIdx.x * 128;
    int wm = (wv >> 1) * 64,  wn = (wv & 1) * 64;

    f32x4 acc[4][4] = {};
    int srow = tid >> 2, scol = (tid & 3) * 8;

    for (int k0 = 0; k0 < 1024; k0 += 32) {
        #pragma unroll
        for (int s = 0; s < 2; ++s) {
            int row = s * 64 + srow;
            gl_lds16(&A[(size_t)(bm + row) * 1024 + k0 + scol], &As[(s * 256 + wv * 64) * 8]);
            gl_lds16(&Bt[(size_t)(bn + row) * 3072 + k0 + scol], &Bs[(s * 256 + wv * 64) * 8]);
        }
        __syncthreads();
        bf16x8 af[4], bfv[4];
        #pragma unroll
        for (int mi = 0; mi < 4; ++mi)
            af[mi] = *reinterpret_cast<const bf16x8*>(&As[(wm + mi * 16 + l16) * 32 + quad * 8]);
        #pragma unroll
        for (int ni = 0; ni < 4; ++ni)
            bfv[ni] = *reinterpret_cast<const bf16x8*>(&Bs[(wn + ni * 16 + l16) * 32 + quad * 8]);
        #pragma unroll
        for (int mi = 0; mi < 4; ++mi)
            #pragma unroll
            for (int ni = 0; ni < 4; ++ni)
                acc[mi][ni] = __builtin_amdgcn_mfma_f32_16x16x32_bf16(af[mi], bfv[ni], acc[mi][ni], 0, 0, 0);
        __syncthreads();
    }

    #pragma unroll
    for (int mi = 0; mi < 4; ++mi)
        #pragma unroll
        for (int ni = 0; ni < 4; ++ni) {
            int col = bn + wn + ni * 16 + l16;
            #pragma unroll
            for (int ri = 0; ri < 4; ++ri) {
                int row = bm + wm + mi * 16 + quad * 4 + ri;
                out[(size_t)row * 1024 + col] = f2bf(acc[mi][ni][ri] * scale);
            }
        }
}

// ---------------- bias fold ----------------
__global__ void k_foldb(const unsigned short* __restrict__ wT3, const float* __restrict__ bc,
                        const float* __restrict__ qb, const float* __restrict__ kb,
                        const float* __restrict__ vb, float* __restrict__ beff)
{
    int id = blockIdx.x * blockDim.x + threadIdx.x;  // 0..3071
    int z = id >> 10, n = id & 1023;
    const unsigned short* row = wT3 + (size_t)z * 1024 * 1024 + (size_t)n * 1024;
    const float* b2 = (z == 0) ? qb : (z == 1) ? kb : vb;
    float s = 0.f;
    for (int c = 0; c < 1024; ++c) s += bc[z * 1024 + c] * bf2f(row[c]);
    s += b2[n];
    if (z == 0) s *= 0.1803368801f;
    beff[id] = s;
}

// ---------------- fused projections: x @ W_eff[z] + b_eff[z] -> gathered layouts ----------------
__global__ __launch_bounds__(256) void k_gemm3(
    const unsigned short* __restrict__ A,      // xb [8192][1024]
    const unsigned short* __restrict__ Weff,   // [3][1024][1024]
    const float* __restrict__ beff,            // [3][1024]
    unsigned short* __restrict__ Qg, unsigned short* __restrict__ Kg,
    unsigned short* __restrict__ Vtg)
{
    __shared__ unsigned short smem[8320];      // As(4096)+Bs(4096) in-loop; Vt[64][130] in epilogue
    unsigned short* As = smem;
    unsigned short* Bs = smem + 4096;
    int z = blockIdx.z;
    const unsigned short* Bt = Weff + (size_t)z * 1024 * 1024;
    const float* bias = beff + z * 1024;

    int tid  = threadIdx.x;
    int lane = tid & 63, wv = tid >> 6;
    int quad = lane >> 4, l16 = lane & 15;
    int bm = blockIdx.y * 128, bn = blockIdx.x * 128;
    int wm = (wv >> 1) * 64,  wn = (wv & 1) * 64;

    f32x4 acc[4][4] = {};
    int srow = tid >> 2, scol = (tid & 3) * 8;

    for (int k0 = 0; k0 < 1024; k0 += 32) {
        #pragma unroll
        for (int s = 0; s < 2; ++s) {
            int row = s * 64 + srow;
            gl_lds16(&A[(size_t)(bm + row) * 1024 + k0 + scol], &As[(s * 256 + wv * 64) * 8]);
            gl_lds16(&Bt[(size_t)(bn + row) * 1024 + k0 + scol], &Bs[(s * 256 + wv * 64) * 8]);
        }
        __syncthreads();
        bf16x8 af[4], bfv[4];
        #pragma unroll
        for (int mi = 0; mi < 4; ++mi)
            af[mi] = *reinterpret_cast<const bf16x8*>(&As[(wm + mi * 16 + l16) * 32 + quad * 8]);
        #pragma unroll
        for (int ni = 0; ni < 4; ++ni)
            bfv[ni] = *reinterpret_cast<const bf16x8*>(&Bs[(wn + ni * 16 + l16) * 32 + quad * 8]);
        #pragma unroll
        for (int mi = 0; mi < 4; ++mi)
            #pragma unroll
            for (int ni = 0; ni < 4; ++ni)
                acc[mi][ni] = __builtin_amdgcn_mfma_f32_16x16x32_bf16(af[mi], bfv[ni], acc[mi][ni], 0, 0, 0);
        __syncthreads();
    }

    if (z < 2) {
        unsigned short* dst = (z == 0) ? Qg : Kg;
        #pragma unroll
        for (int mi = 0; mi < 4; ++mi)
            #pragma unroll
            for (int ni = 0; ni < 4; ++ni) {
                int col = bn + wn + ni * 16 + l16;
                float bsv = bias[col];
                int hh = col >> 6, d = col & 63;
                #pragma unroll
                for (int ri = 0; ri < 4; ++ri) {
                    int row = bm + wm + mi * 16 + quad * 4 + ri;
                    unsigned short bv = f2bf(acc[mi][ni][ri] + bsv);
                    int b = row >> 12, t = row & 4095;
                    int bh = b * 16 + hh;
                    { int slot = t >> 9, idx = t & 511;
                      dst[((size_t)(slot * 32 + bh) * 512 + idx) * 64 + d] = bv; }
                    if (((t ^ hh) & 1) == 0) {
                        int slot = 8 + (t >> 10), idx = (t & 1023) >> 1;
                        dst[((size_t)(slot * 32 + bh) * 512 + idx) * 64 + d] = bv;
                    }
                    if (((t ^ hh) & 3) == 0) {
                        int slot = 12 + (t >> 11), idx = (t & 2047) >> 2;
                        dst[((size_t)(slot * 32 + bh) * 512 + idx) * 64 + d] = bv;
                    }
                }
            }
    } else {
        unsigned short* Vt = smem;            // [64 d][130]
        int b = bm >> 12, t0 = bm & 4095;
        #pragma unroll
        for (int half = 0; half < 2; ++half) {
            if ((wn >> 6) == half) {
                #pragma unroll
                for (int mi = 0; mi < 4; ++mi)
                    #pragma unroll
                    for (int ni = 0; ni < 4; ++ni) {
                        int col = bn + wn + ni * 16 + l16;
                        float bsv = bias[col];
                        int din = ni * 16 + l16;
                        #pragma unroll
                        for (int ri = 0; ri < 4; ++ri) {
                            int rowt = wm + mi * 16 + quad * 4 + ri;
                            Vt[din * 130 + rowt] = f2bf(acc[mi][ni][ri] + bsv);
                        }
                    }
            }
            __syncthreads();
            int d = tid >> 2, part = tid & 3;
            int h_glob = (bn >> 6) + half;
            int bh = b * 16 + h_glob;
            const unsigned short* lrow = &Vt[d * 130];
            {   // branch 0: 128 contiguous idx
                int slot = t0 >> 9;
                size_t dst = ((size_t)(slot * 32 + bh) * 64 + d) * 512 + (t0 & 511) + part * 32;
                unsigned short buf[32];
                #pragma unroll
                for (int j = 0; j < 32; ++j) buf[j] = lrow[part * 32 + j];
                #pragma unroll
                for (int j = 0; j < 4; ++j)
                    *reinterpret_cast<uint4*>(&Vtg[dst + j * 8]) = reinterpret_cast<const uint4*>(buf)[j];
            }
            {   // branch 1
                int j0 = h_glob & 1;
                int slot = 8 + (t0 >> 10);
                size_t dst = ((size_t)(slot * 32 + bh) * 64 + d) * 512 + ((t0 & 1023) >> 1) + part * 16;
                unsigned short buf[16];
                #pragma unroll
                for (int j = 0; j < 16; ++j) buf[j] = lrow[j0 + 2 * (part * 16 + j)];
                #pragma unroll
                for (int j = 0; j < 2; ++j)
                    *reinterpret_cast<uint4*>(&Vtg[dst + j * 8]) = reinterpret_cast<const uint4*>(buf)[j];
            }
            {   // branch 2
                int j0 = h_glob & 3;
                int slot = 12 + (t0 >> 11);
                size_t dst = ((size_t)(slot * 32 + bh) * 64 + d) * 512 + ((t0 & 2047) >> 2) + part * 8;
                unsigned short buf[8];
                #pragma unroll
                for (int j = 0; j < 8; ++j) buf[j] = lrow[j0 + 4 * (part * 8 + j)];
                *reinterpret_cast<uint4*>(&Vtg[dst]) = *reinterpret_cast<const uint4*>(buf);
            }
            __syncthreads();
        }
    }
}

// ---------------- dilated attention: paired q-tiles, LDS K/V, register double-buffer prefetch ----------------
// grid (2 pairs, 14 slots, 32 bh), block 256. Block pq owns q-tiles {pq, 3-pq} (balanced).
// Next jt's K/V tile is preloaded into registers while current jt computes (global latency hidden).
// launch_bounds (256,3): 170-VGPR budget — no spill (r8's (256,5) forced 48 VGPRs and spilled).
__global__ __launch_bounds__(256, 3) void k_attn(
    const unsigned short* __restrict__ Qg,
    const unsigned short* __restrict__ Kg,
    const unsigned short* __restrict__ Vtg,
    unsigned short* __restrict__ Og,
    float* __restrict__ Lg)
{
    __shared__ unsigned short Ks[64 * 72];
    __shared__ unsigned short Vs[64 * 72];      // [d][kcol] (pre-transposed in global)
    __shared__ unsigned short Ps[4][16 * 72];   // per-wave P buffer

    int tid  = threadIdx.x;
    int lane = tid & 63, wv = tid >> 6;
    int quad = lane >> 4, l16 = lane & 15;
    int pq = blockIdx.x, ys = blockIdx.y, bh = blockIdx.z;
    int jt_end = 2 * (3 - pq) + 1;    // 7 (pair 0,3) or 5 (pair 1,2)
    size_t sb = (size_t)(ys * 32 + bh) * (512 * 64);
    const unsigned short* qp = Qg + sb;
    const unsigned short* kp = Kg + sb;
    const unsigned short* vp = Vtg + sb;
    unsigned short* op = Og + sb;
    float* lp = Lg + (size_t)(ys * 32 + bh) * 512;
    unsigned short* pw = Ps[wv];

    int rw[2] = { pq * 128 + wv * 32, (3 - pq) * 128 + wv * 32 };

    // staging geometry: thread covers rows {srow, srow+32} cols sc8..sc8+7
    int srow = tid >> 3, sc8 = (tid & 7) * 8;
    uint4 kr[2], vr[2];
    {   // preload jt = 0
        #pragma unroll
        for (int s = 0; s < 2; ++s) {
            int row = s * 32 + srow;
            kr[s] = *reinterpret_cast<const uint4*>(&kp[(size_t)row * 64 + sc8]);
            vr[s] = *reinterpret_cast<const uint4*>(&vp[(size_t)row * 512 + sc8]);
        }
    }

    bf16x8 qf[2][2][2];
    #pragma unroll
    for (int qi = 0; qi < 2; ++qi)
        #pragma unroll
        for (int m16 = 0; m16 < 2; ++m16)
            #pragma unroll
            for (int kk = 0; kk < 2; ++kk)
                qf[qi][m16][kk] = *reinterpret_cast<const bf16x8*>(
                    &qp[(size_t)(rw[qi] + m16 * 16 + l16) * 64 + kk * 32 + quad * 8]);

    f32x4 acc[2][2][4] = {};
    float l4[2][2][4] = {};

    for (int jt = 0; jt <= jt_end; ++jt) {
        __syncthreads();   // prior-iter K/V reads done before overwrite
        #pragma unroll
        for (int s = 0; s < 2; ++s) {
            int row = s * 32 + srow;
            *reinterpret_cast<uint4*>(&Ks[row * 72 + sc8]) = kr[s];
            *reinterpret_cast<uint4*>(&Vs[row * 72 + sc8]) = vr[s];
        }
        if (jt < jt_end) {   // prefetch next tile into regs; loads fly during compute below
            #pragma unroll
            for (int s = 0; s < 2; ++s) {
                int row = s * 32 + srow;
                kr[s] = *reinterpret_cast<const uint4*>(&kp[(size_t)((jt + 1) * 64 + row) * 64 + sc8]);
                vr[s] = *reinterpret_cast<const uint4*>(&vp[(size_t)row * 512 + (jt + 1) * 64 + sc8]);
            }
        }
        __syncthreads();

        #pragma unroll
        for (int qi = 0; qi < 2; ++qi) {
            #pragma unroll
            for (int m16 = 0; m16 < 2; ++m16) {
                int rowbase = rw[qi] + m16 * 16;
                if (jt * 64 > rowbase + 15) continue;

                f32x4 sacc[4];
                #pragma unroll
                for (int nt = 0; nt < 4; ++nt) {
                    bf16x8 b0 = *reinterpret_cast<const bf16x8*>(&Ks[(nt * 16 + l16) * 72 + quad * 8]);
                    bf16x8 b1 = *reinterpret_cast<const bf16x8*>(&Ks[(nt * 16 + l16) * 72 + 32 + quad * 8]);
                    f32x4 s4 = {};
                    s4 = __builtin_amdgcn_mfma_f32_16x16x32_bf16(qf[qi][m16][0], b0, s4, 0, 0, 0);
                    s4 = __builtin_amdgcn_mfma_f32_16x16x32_bf16(qf[qi][m16][1], b1, s4, 0, 0, 0);
                    sacc[nt] = s4;
                }
                if (jt * 64 + 63 > rowbase) {
                    #pragma unroll
                    for (int nt = 0; nt < 4; ++nt)
                        #pragma unroll
                        for (int ri = 0; ri < 4; ++ri) {
                            int kj = jt * 64 + nt * 16 + l16, qi2 = rowbase + quad * 4 + ri;
                            if (kj > qi2) sacc[nt][ri] = -1e30f;
                        }
                }
                #pragma unroll
                for (int nt = 0; nt < 4; ++nt)
                    #pragma unroll
                    for (int ri = 0; ri < 4; ++ri) {
                        float p = exp2f(sacc[nt][ri]);
                        sacc[nt][ri] = p;
                        l4[qi][m16][ri] += p;
                    }
                #pragma unroll
                for (int j = 0; j < 4; ++j) {
                    int nt = (j + quad) & 3;
                    #pragma unroll
                    for (int ri = 0; ri < 4; ++ri)
                        pw[(quad * 4 + ri) * 72 + nt * 16 + l16] = f2bf(sacc[nt][ri]);
                }
                bf16x8 pf[2];
                #pragma unroll
                for (int kk = 0; kk < 2; ++kk)
                    pf[kk] = *reinterpret_cast<const bf16x8*>(&pw[l16 * 72 + kk * 32 + quad * 8]);
                #pragma unroll
                for (int dt = 0; dt < 4; ++dt) {
                    bf16x8 v0 = *reinterpret_cast<const bf16x8*>(&Vs[(dt * 16 + l16) * 72 + quad * 8]);
                    bf16x8 v1 = *reinterpret_cast<const bf16x8*>(&Vs[(dt * 16 + l16) * 72 + 32 + quad * 8]);
                    f32x4 a4 = acc[qi][m16][dt];
                    a4 = __builtin_amdgcn_mfma_f32_16x16x32_bf16(pf[0], v0, a4, 0, 0, 0);
                    a4 = __builtin_amdgcn_mfma_f32_16x16x32_bf16(pf[1], v1, a4, 0, 0, 0);
                    acc[qi][m16][dt] = a4;
                }
            }
        }
    }

    #pragma unroll
    for (int qi = 0; qi < 2; ++qi)
        #pragma unroll
        for (int m16 = 0; m16 < 2; ++m16) {
            #pragma unroll
            for (int ri = 0; ri < 4; ++ri) {
                float l = l4[qi][m16][ri];
                l += __shfl_xor(l, 1);
                l += __shfl_xor(l, 2);
                l += __shfl_xor(l, 4);
                l += __shfl_xor(l, 8);
                l4[qi][m16][ri] = l;
            }
            #pragma unroll
            for (int dt = 0; dt < 4; ++dt)
                #pragma unroll
                for (int ri = 0; ri < 4; ++ri) {
                    int row = rw[qi] + m16 * 16 + quad * 4 + ri;
                    op[(size_t)row * 64 + dt * 16 + l16] = f2bf(acc[qi][m16][dt][ri] / l4[qi][m16][ri]);
                }
            if (l16 == 0) {
                #pragma unroll
                for (int ri = 0; ri < 4; ++ri) {
                    int row = rw[qi] + m16 * 16 + quad * 4 + ri;
                    lp[row] = __logf(l4[qi][m16][ri]);
                }
            }
        }
}

// ---------------- combine branches via LSE weights ----------------
__global__ void k_combine(const unsigned short* __restrict__ Og,
                          const float* __restrict__ Lg,
                          unsigned short* __restrict__ yb)
{
    int g   = blockIdx.x * blockDim.x + threadIdx.x;
    int row = g >> 3;
    int d0  = (g & 7) * 8;
    int bh = row >> 12, t = row & 4095;
    int b = bh >> 4, h = bh & 15;

    int slot0 = t >> 9,         idx0 = t & 511;
    int slot1 = 8 + (t >> 10),  idx1 = (t & 1023) >> 1;
    int slot2 = 12 + (t >> 11), idx2 = (t & 2047) >> 2;
    size_t r0 = (size_t)(slot0 * 32 + bh) * 512 + idx0;
    size_t r1 = (size_t)(slot1 * 32 + bh) * 512 + idx1;
    size_t r2 = (size_t)(slot2 * 32 + bh) * 512 + idx2;
    bool c1 = ((t ^ h) & 1) == 0;
    bool c2 = ((t ^ h) & 3) == 0;

    float L0 = Lg[r0];
    float L1 = c1 ? Lg[r1] : -1e30f;
    float L2 = c2 ? Lg[r2] : -1e30f;
    float m  = fmaxf(L0, fmaxf(L1, L2));
    float w0 = __expf(L0 - m), w1 = __expf(L1 - m), w2 = __expf(L2 - m);
    float inv = 1.f / (w0 + w1 + w2);

    uint4 v0 = *reinterpret_cast<const uint4*>(&Og[r0 * 64 + d0]);
    uint4 v1 = *reinterpret_cast<const uint4*>(&Og[r1 * 64 + d0]);
    uint4 v2 = *reinterpret_cast<const uint4*>(&Og[r2 * 64 + d0]);
    const unsigned short* p0 = reinterpret_cast<const unsigned short*>(&v0);
    const unsigned short* p1 = reinterpret_cast<const unsigned short*>(&v1);
    const unsigned short* p2 = reinterpret_cast<const unsigned short*>(&v2);
    unsigned short o[8];
    #pragma unroll
    for (int u = 0; u < 8; ++u)
        o[u] = f2bf((w0 * bf2f(p0[u]) + w1 * bf2f(p1[u]) + w2 * bf2f(p2[u])) * inv);
    size_t yidx = (((size_t)b * 4096 + t) * 1024) + (size_t)h * 64 + d0;
    *reinterpret_cast<uint4*>(&yb[yidx]) = *reinterpret_cast<const uint4*>(o);
}

extern "C" void kernel_launch(void* const* d_in, const int* in_sizes, int n_in,
                              void* d_out, int out_size, void* d_ws, size_t ws_size,
                              hipStream_t stream)
{
    const float* x        = (const float*)d_in[0];
    const float* c_attn_w = (const float*)d_in[1];
    const float* c_attn_b = (const float*)d_in[2];
    const float* q_w      = (const float*)d_in[3];
    const float* q_b      = (const float*)d_in[4];
    const float* k_w      = (const float*)d_in[5];
    const float* k_b      = (const float*)d_in[6];
    const float* v_w      = (const float*)d_in[7];
    const float* v_b      = (const float*)d_in[8];
    const float* o_w      = (const float*)d_in[9];
    const float* o_b      = (const float*)d_in[10];

    char* ws = (char*)d_ws;
    size_t off = 0;
    auto alloc = [&](size_t bytes) -> char* {
        char* p = ws + off; off += (bytes + 255) & ~(size_t)255; return p;
    };
    const size_t GSZ = 14ull * 32 * 512 * 64;
    unsigned short* xb    = (unsigned short*)alloc(8192ull * 1024 * 2);
    unsigned short* WcB   = (unsigned short*)alloc(1024ull * 3072 * 2);   // c_attn_w bf16, untransposed
    unsigned short* wqT   = (unsigned short*)alloc(1024ull * 1024 * 2);   // q/k/v contiguous
    unsigned short* wkT   = (unsigned short*)alloc(1024ull * 1024 * 2);
    unsigned short* wvT   = (unsigned short*)alloc(1024ull * 1024 * 2);
    unsigned short* woT   = (unsigned short*)alloc(1024ull * 1024 * 2);
    unsigned short* Weff  = (unsigned short*)alloc(3ull * 1024 * 1024 * 2);
    float*          beff  = (float*)alloc(3ull * 1024 * 4);
    unsigned short* Qg    = (unsigned short*)alloc(GSZ * 2);
    unsigned short* Kg    = (unsigned short*)alloc(GSZ * 2);
    unsigned short* Vtg   = (unsigned short*)alloc(GSZ * 2);
    unsigned short* Og    = (unsigned short*)alloc(GSZ * 2);
    float*          Lg    = (float*)alloc(14ull * 32 * 512 * 4);
    unsigned short* yb    = xb;   // alias: xb dead after k_gemm3
    (void)wkT; (void)wvT;

    // 1. casts
    k_cast<<<(8192 * 1024) / 1024, 256, 0, stream>>>(x, xb, 8192 * 1024);
    k_cast<<<(1024 * 3072) / 1024, 256, 0, stream>>>(c_attn_w, WcB, 1024 * 3072);
    // 2. transpose-cast q/k/v/o weights (one dispatch)
    k_transpose4<<<dim3(32, 32, 4), dim3(32, 8), 0, stream>>>(q_w, k_w, v_w, o_w, wqT, wkT, wvT, woT);
    // 3. weight/bias folding
    k_foldw<<<dim3(8, 8, 3), 256, 0, stream>>>(wqT, WcB, Weff);
    k_foldb<<<12, 256, 0, stream>>>(wqT, c_attn_b, q_b, k_b, v_b, beff);
    // 4. fused projections: x -> gathered Q/K/V^T
    k_gemm3<<<dim3(8, 64, 3), 256, 0, stream>>>(xb, Weff, beff, Qg, Kg, Vtg);
    // 5. attention (paired q-tiles, register-prefetch double buffer)
    k_attn<<<dim3(2, 14, 32), 256, 0, stream>>>(Qg, Kg, Vtg, Og, Lg);
    // 6. combine -> y
    k_combine<<<4096, 256, 0, stream>>>(Og, Lg, yb);
    // 7. out = y @ o_w + o_b (fp32)
    k_gemm<<<dim3(8, 64), 256, 0, stream>>>(yb, 1024, woT, 1024, o_b, d_out, 8192, 1024, 1024, 2, 1.f);
}